// Round 7
// baseline (622.232 us; speedup 1.0000x reference)
//
#include <hip/hip_runtime.h>
#include <hip/hip_bf16.h>
#include <stdint.h>

// Problem constants
#define B_    2
#define S_    2048
#define HID_  2048
#define H_    16
#define KV_   2
#define D_    128
#define ROT_  32
#define NQG   4096   // H*2D
#define NKV   256    // KV*D
#define SCALE_ 0.08838834764831845f  // D^-0.5

typedef __attribute__((ext_vector_type(8))) short  short8;
typedef __attribute__((ext_vector_type(4))) float  floatx4;

__device__ __forceinline__ float b2f(unsigned short u) {
  union { unsigned int i; float f; } v; v.i = ((unsigned int)u) << 16; return v.f;
}
__device__ __forceinline__ unsigned short f2b(float f) {
  union { float f; unsigned int i; } v; v.f = f;
  return (unsigned short)((v.i + 0x7fffu + ((v.i >> 16) & 1u)) >> 16);
}

// ---------------- fp32 -> bf16 elementwise convert (8 elems/thread) ----------------
__global__ __launch_bounds__(256) void k_cvt(const float* __restrict__ in,
                                             unsigned short* __restrict__ out, long n) {
  long i0 = ((long)blockIdx.x * 256 + threadIdx.x) * 8;
  if (i0 >= n) return;
  float4 a = *(const float4*)(in + i0);
  float4 b = *(const float4*)(in + i0 + 4);
  short8 v;
  v[0] = (short)f2b(a.x); v[1] = (short)f2b(a.y);
  v[2] = (short)f2b(a.z); v[3] = (short)f2b(a.w);
  v[4] = (short)f2b(b.x); v[5] = (short)f2b(b.y);
  v[6] = (short)f2b(b.z); v[7] = (short)f2b(b.w);
  *(short8*)(out + i0) = v;
}

// ---------------- prep: gamma/eta + folded key bias ----------------
__global__ __launch_bounds__(256) void k_prep(const float* __restrict__ prior,
                                              float* __restrict__ ge,
                                              float* __restrict__ kbias) {
  int i = blockIdx.x * 256 + threadIdx.x;
  if (i >= S_) return;
  float p  = prior[i];
  float pc = p * (float)S_;
  float g  = 1.0f + 0.1f * (pc - 1.0f);
  g = fminf(fmaxf(g, 0.9f), 1.1f);
  ge[i] = g;
  float cb = fminf(fmaxf(p, -3.0f), 3.0f);
  kbias[i] = cb + logf(1.0f + 0.5f * pc);
}

// ---------------- transpose + convert: out_bf16[C][R] = in_fp32[R][C] ----------------
__global__ __launch_bounds__(256) void k_transpose(const float* __restrict__ in,
                                                   unsigned short* __restrict__ out,
                                                   int R, int C) {
  __shared__ unsigned short tile[64][68];
  int tx = threadIdx.x & 15, ty = threadIdx.x >> 4;
  long c0 = (long)blockIdx.x * 64, r0 = (long)blockIdx.y * 64;
#pragma unroll
  for (int i = 0; i < 4; i++) {
    int row = ty + 16 * i;
    const float* src = in + (r0 + row) * C + c0 + 4 * tx;
    float4 v = *(const float4*)src;
    tile[row][4 * tx + 0] = f2b(v.x);
    tile[row][4 * tx + 1] = f2b(v.y);
    tile[row][4 * tx + 2] = f2b(v.z);
    tile[row][4 * tx + 3] = f2b(v.w);
  }
  __syncthreads();
#pragma unroll
  for (int i = 0; i < 4; i++) {
    int oc = ty + 16 * i;
    ushort4 v;
    v.x = tile[4 * tx + 0][oc];
    v.y = tile[4 * tx + 1][oc];
    v.z = tile[4 * tx + 2][oc];
    v.w = tile[4 * tx + 3][oc];
    *(ushort4*)(out + (c0 + oc) * R + r0 + 4 * tx) = v;
  }
}

// ---------------- GEMM: C[M][N] = A[M][K] @ Bt[N][K]^T ----------------
template <int OUT32>
__global__ __launch_bounds__(256) void k_gemm_bt(const unsigned short* __restrict__ A,
                                                 const unsigned short* __restrict__ Bt,
                                                 void* __restrict__ Cv,
                                                 int M, int N, int K) {
  __shared__ __align__(16) unsigned short As[128 * 40];
  __shared__ __align__(16) unsigned short Bs[128 * 40];
  const int t    = threadIdx.x;
  const int lane = t & 63;
  const int wv   = t >> 6;
  const int wm   = wv >> 1, wn = wv & 1;
  const long m0  = (long)blockIdx.y * 128;
  const long n0  = (long)blockIdx.x * 128;
  const int r15  = lane & 15, g4 = lane >> 4;
  const int row0 = t >> 2, cb = t & 3;

  const unsigned short* Ap0 = A  + (m0 + row0)      * K + cb * 8;
  const unsigned short* Ap1 = A  + (m0 + row0 + 64) * K + cb * 8;
  const unsigned short* Bp0 = Bt + (n0 + row0)      * K + cb * 8;
  const unsigned short* Bp1 = Bt + (n0 + row0 + 64) * K + cb * 8;

  floatx4 acc[4][4];
#pragma unroll
  for (int m = 0; m < 4; m++)
#pragma unroll
    for (int n = 0; n < 4; n++) acc[m][n] = (floatx4){0.f, 0.f, 0.f, 0.f};

  short8 va0 = *(const short8*)(Ap0);
  short8 va1 = *(const short8*)(Ap1);
  short8 vb0 = *(const short8*)(Bp0);
  short8 vb1 = *(const short8*)(Bp1);

  for (int k0 = 0; k0 < K; k0 += 32) {
    *(short8*)(&As[row0 * 40 + cb * 8])        = va0;
    *(short8*)(&As[(row0 + 64) * 40 + cb * 8]) = va1;
    *(short8*)(&Bs[row0 * 40 + cb * 8])        = vb0;
    *(short8*)(&Bs[(row0 + 64) * 40 + cb * 8]) = vb1;
    __syncthreads();
    if (k0 + 32 < K) {
      va0 = *(const short8*)(Ap0 + k0 + 32);
      va1 = *(const short8*)(Ap1 + k0 + 32);
      vb0 = *(const short8*)(Bp0 + k0 + 32);
      vb1 = *(const short8*)(Bp1 + k0 + 32);
    }
    short8 af[4], bf[4];
#pragma unroll
    for (int m = 0; m < 4; m++)
      af[m] = *(const short8*)(&As[(wm * 64 + m * 16 + r15) * 40 + g4 * 8]);
#pragma unroll
    for (int n = 0; n < 4; n++)
      bf[n] = *(const short8*)(&Bs[(wn * 64 + n * 16 + r15) * 40 + g4 * 8]);
#pragma unroll
    for (int m = 0; m < 4; m++)
#pragma unroll
      for (int n = 0; n < 4; n++)
        acc[m][n] = __builtin_amdgcn_mfma_f32_16x16x32_bf16(af[m], bf[n], acc[m][n], 0, 0, 0);
    __syncthreads();
  }

#pragma unroll
  for (int m = 0; m < 4; m++) {
    const long rbase = m0 + wm * 64 + m * 16 + g4 * 4;
#pragma unroll
    for (int n = 0; n < 4; n++) {
      const long cidx = n0 + wn * 64 + n * 16 + r15;
#pragma unroll
      for (int i = 0; i < 4; i++) {
        if (OUT32) ((float*)Cv)[(rbase + i) * N + cidx] = acc[m][n][i];
        else ((unsigned short*)Cv)[(rbase + i) * N + cidx] = f2b(acc[m][n][i]);
      }
    }
  }
}

// ---------------- q/k postprocess: RMS + RoPE (+gamma for k); K written in fragment-major kF ----------------
__global__ __launch_bounds__(256) void k_qkpost(const unsigned short* __restrict__ qg,
                                                const unsigned short* __restrict__ kraw,
                                                const float* __restrict__ cosb,
                                                const float* __restrict__ sinb,
                                                const float* __restrict__ ge,
                                                const float* __restrict__ qnw,
                                                const float* __restrict__ knw,
                                                unsigned short* __restrict__ qT,
                                                unsigned short* __restrict__ kF) {
  int wid  = (blockIdx.x * 256 + threadIdx.x) >> 6;
  int lane = threadIdx.x & 63;
  int r    = wid % (H_ + KV_);
  long bs  = wid / (H_ + KV_);
  if (bs >= (long)B_ * S_) return;
  int b = (int)(bs >> 11), s = (int)(bs & 2047);
  int d0 = lane * 2;

  float x0, x1;
  if (r < H_) {
    const unsigned short* src = qg + bs * NQG + r * 256 + d0;
    x0 = b2f(src[0]); x1 = b2f(src[1]);
  } else {
    const unsigned short* src = kraw + bs * NKV + (r - H_) * 128 + d0;
    x0 = b2f(src[0]); x1 = b2f(src[1]);
  }
  float ss = x0 * x0 + x1 * x1;
#pragma unroll
  for (int mask = 1; mask < 64; mask <<= 1) ss += __shfl_xor(ss, mask);
  float rstd = rsqrtf(ss * (1.0f / 128.0f) + 1e-6f);
  float w0, w1;
  if (r < H_) { w0 = qnw[d0]; w1 = qnw[d0 + 1]; }
  else        { w0 = knw[d0]; w1 = knw[d0 + 1]; }
  float xn0 = x0 * rstd * w0, xn1 = x1 * rstd * w1;
  float p0 = __shfl_xor(xn0, 8), p1 = __shfl_xor(xn1, 8);
  float y0 = xn0, y1 = xn1;
  if (lane < 16) {
    float c0 = cosb[bs * ROT_ + d0], c1 = cosb[bs * ROT_ + d0 + 1];
    float s0 = sinb[bs * ROT_ + d0], s1 = sinb[bs * ROT_ + d0 + 1];
    float sgn = (lane < 8) ? -1.0f : 1.0f;
    y0 = xn0 * c0 + sgn * p0 * s0;
    y1 = xn1 * c1 + sgn * p1 * s1;
  }
  if (r < H_) {
    unsigned int pack = (unsigned int)f2b(y0) | ((unsigned int)f2b(y1) << 16);
    *(unsigned int*)(qT + ((long)(b * H_ + r) * S_ + s) * D_ + d0) = pack;
  } else {
    float g = ge[s];
    unsigned int pack = (unsigned int)f2b(y0 * g) | ((unsigned int)f2b(y1 * g) << 16);
    int kvb = r - H_;
    // fragment-major: lane l of fragment (s/16, d/32) holds K[s][d], l = (s&15) + ((d>>3)&3)*16
    size_t off = (size_t)(b * KV_ + kvb) * 262144
               + (size_t)((s >> 4) * 4 + (d0 >> 5)) * 512
               + (size_t)(((s & 15) + (((d0 >> 3) & 3)) * 16)) * 8 + (d0 & 7);
    *(unsigned int*)(kF + off) = pack;
  }
}

// ---------------- v postprocess: scale by eta, write fragment-major vF ----------------
__global__ __launch_bounds__(256) void k_vpost(const unsigned short* __restrict__ vraw,
                                               const float* __restrict__ ge,
                                               unsigned short* __restrict__ vF) {
  int bx  = blockIdx.x;
  int scn = bx & 7, d = (bx >> 3) & 127, kvb = (bx >> 10) & 1, b = bx >> 11;
  int s = scn * 256 + threadIdx.x;
  float v = b2f(vraw[((long)(b * S_ + s)) * NKV + kvb * 128 + d]);
  v *= ge[s];
  // fragment-major: chunk (s/64, d/16, (s/32)&1), lane l = (d&15) + ((s>>3)&3)*16, elem = s&7
  size_t off = (size_t)(b * KV_ + kvb) * 262144
             + (size_t)((s >> 6) * 16 + (d >> 4) * 2 + ((s >> 5) & 1)) * 512
             + (size_t)((d & 15) + ((s >> 3) & 3) * 16) * 8 + (s & 7);
  vF[off] = f2b(v);
}

// ---------------- flash attention: 1 wave, 16 q-rows, 2 heads (shared K/V), coalesced kF/vF ----------------
// VAR 0: full (real output).  Ablations (scratch out, heavy 256-block subset):
// VAR 1: no PV (QK+softmax only).  VAR 2: no softmax (QK+PV).  VAR 3: loads only.
template <int VAR>
__global__ __launch_bounds__(64) void k_attn(const unsigned short* __restrict__ qT,
                                             const unsigned short* __restrict__ kF,
                                             const unsigned short* __restrict__ vF,
                                             const float* __restrict__ kbias,
                                             const unsigned short* __restrict__ qg,
                                             unsigned short* __restrict__ ag) {
  __shared__ __align__(16) unsigned short Ps[2][16 * 88];
  const int lane = threadIdx.x;
  const int r15 = lane & 15, g4 = lane >> 4;
  const int p = blockIdx.x;
  const int xcd = p & 7;
  const int grp = xcd >> 1;                         // (b,kvh): 2 XCDs per group
  const int mem = ((p >> 3) << 1) | (xcd & 1);
  const int hp = mem & 3;                           // head pair
  const int strip = 127 - (mem >> 2);               // heavy strips first
  const int b = grp >> 1, kvh = grp & 1;
  const int hh0 = kvh * 8 + hp * 2;
  const int q0s = strip * 16;

  const unsigned short* kFg = kF + (size_t)(b * KV_ + kvh) * 262144;
  const unsigned short* vFg = vF + (size_t)(b * KV_ + kvh) * 262144;

  short8 qf[2][4];
#pragma unroll
  for (int hd = 0; hd < 2; hd++) {
    const unsigned short* qp = qT + ((long)(b * H_ + hh0 + hd) * S_ + q0s + r15) * D_ + g4 * 8;
#pragma unroll
    for (int kb = 0; kb < 4; kb++) qf[hd][kb] = *(const short8*)(qp + kb * 32);
  }

  floatx4 oacc[2][8];
#pragma unroll
  for (int hd = 0; hd < 2; hd++)
#pragma unroll
    for (int nd = 0; nd < 8; nd++) oacc[hd][nd] = (floatx4){0.f, 0.f, 0.f, 0.f};
  float mrow[2] = {-1e30f, -1e30f}, lrw[2] = {0.f, 0.f};
  float fdum = 0.f;
  short8 dx = (short8){0, 0, 0, 0, 0, 0, 0, 0};

  const int ntiles = (strip >> 2) + 1;
  for (int tile = 0; tile < ntiles; tile++) {
    const int j0 = tile * 64;
    const unsigned short* kt = kFg + (size_t)(j0 >> 4) * 2048 + lane * 8;
    const unsigned short* vt = vFg + (size_t)(j0 >> 6) * 8192 + lane * 8;

    floatx4 sacc[2][4];
#pragma unroll
    for (int hd = 0; hd < 2; hd++)
#pragma unroll
      for (int n = 0; n < 4; n++) sacc[hd][n] = (floatx4){0.f, 0.f, 0.f, 0.f};

    if (VAR != 3) {
#pragma unroll
      for (int n = 0; n < 4; n++) {
        short8 a0 = *(const short8*)(kt + n * 2048);
        short8 a1 = *(const short8*)(kt + n * 2048 + 512);
        short8 a2 = *(const short8*)(kt + n * 2048 + 1024);
        short8 a3 = *(const short8*)(kt + n * 2048 + 1536);
        sacc[0][n] = __builtin_amdgcn_mfma_f32_16x16x32_bf16(a0, qf[0][0], sacc[0][n], 0, 0, 0);
        sacc[0][n] = __builtin_amdgcn_mfma_f32_16x16x32_bf16(a1, qf[0][1], sacc[0][n], 0, 0, 0);
        sacc[0][n] = __builtin_amdgcn_mfma_f32_16x16x32_bf16(a2, qf[0][2], sacc[0][n], 0, 0, 0);
        sacc[0][n] = __builtin_amdgcn_mfma_f32_16x16x32_bf16(a3, qf[0][3], sacc[0][n], 0, 0, 0);
        sacc[1][n] = __builtin_amdgcn_mfma_f32_16x16x32_bf16(a0, qf[1][0], sacc[1][n], 0, 0, 0);
        sacc[1][n] = __builtin_amdgcn_mfma_f32_16x16x32_bf16(a1, qf[1][1], sacc[1][n], 0, 0, 0);
        sacc[1][n] = __builtin_amdgcn_mfma_f32_16x16x32_bf16(a2, qf[1][2], sacc[1][n], 0, 0, 0);
        sacc[1][n] = __builtin_amdgcn_mfma_f32_16x16x32_bf16(a3, qf[1][3], sacc[1][n], 0, 0, 0);
      }
    } else {
#pragma unroll
      for (int n = 0; n < 4; n++) {
        dx ^= *(const short8*)(kt + n * 2048);
        dx ^= *(const short8*)(kt + n * 2048 + 512);
        dx ^= *(const short8*)(kt + n * 2048 + 1024);
        dx ^= *(const short8*)(kt + n * 2048 + 1536);
      }
    }

    const bool last = (tile == ntiles - 1);
    if (VAR == 0 || VAR == 1) {
      float4 kb4[4];
#pragma unroll
      for (int n = 0; n < 4; n++) kb4[n] = *(const float4*)(&kbias[j0 + n * 16 + g4 * 4]);
#pragma unroll
      for (int hd = 0; hd < 2; hd++) {
        float scf[4][4];
#pragma unroll
        for (int n = 0; n < 4; n++)
#pragma unroll
          for (int i = 0; i < 4; i++) {
            float kbv = (i == 0) ? kb4[n].x : (i == 1) ? kb4[n].y : (i == 2) ? kb4[n].z : kb4[n].w;
            float v = sacc[hd][n][i] * SCALE_ + kbv;
            if (last) {
              int jg = j0 + n * 16 + g4 * 4 + i;
              if (jg > q0s + r15) v = -1e30f;
            }
            scf[n][i] = v;
          }
        float pmax = scf[0][0];
#pragma unroll
        for (int n = 0; n < 4; n++)
#pragma unroll
          for (int i = 0; i < 4; i++) pmax = fmaxf(pmax, scf[n][i]);
        pmax = fmaxf(pmax, __shfl_xor(pmax, 16));
        pmax = fmaxf(pmax, __shfl_xor(pmax, 32));
        if (__any(pmax > mrow[hd] + 8.0f)) {
          float mn = fmaxf(mrow[hd], pmax);
          float aq = __expf(mrow[hd] - mn);
          mrow[hd] = mn;
          lrw[hd] *= aq;
          float ai[4];
#pragma unroll
          for (int i = 0; i < 4; i++) ai[i] = __shfl(aq, g4 * 4 + i);
#pragma unroll
          for (int nd = 0; nd < 8; nd++)
#pragma unroll
            for (int i = 0; i < 4; i++) oacc[hd][nd][i] *= ai[i];
        }
        float rsum = 0.f;
#pragma unroll
        for (int n = 0; n < 4; n++)
#pragma unroll
          for (int i = 0; i < 4; i++) {
            float pv = __expf(scf[n][i] - mrow[hd]);
            scf[n][i] = pv;
            rsum += pv;
          }
        rsum += __shfl_xor(rsum, 16);
        rsum += __shfl_xor(rsum, 32);
        lrw[hd] += rsum;
        if (VAR == 0) {
#pragma unroll
          for (int n = 0; n < 4; n++) {
            unsigned int lo = (unsigned int)f2b(scf[n][0]) | ((unsigned int)f2b(scf[n][1]) << 16);
            unsigned int hi = (unsigned int)f2b(scf[n][2]) | ((unsigned int)f2b(scf[n][3]) << 16);
            uint2 w; w.x = lo; w.y = hi;
            *(uint2*)(&Ps[hd][r15 * 88 + n * 16 + g4 * 4]) = w;
          }
        } else {
#pragma unroll
          for (int n = 0; n < 4; n++)
#pragma unroll
            for (int i = 0; i < 4; i++) fdum += scf[n][i];
        }
      }
    } else if (VAR == 2) {  // no softmax: P = raw scores (masked -> 0)
#pragma unroll
      for (int hd = 0; hd < 2; hd++)
#pragma unroll
        for (int n = 0; n < 4; n++) {
          float s0_ = sacc[hd][n][0] * SCALE_, s1_ = sacc[hd][n][1] * SCALE_;
          float s2_ = sacc[hd][n][2] * SCALE_, s3_ = sacc[hd][n][3] * SCALE_;
          if (last) {
            int jgb = j0 + n * 16 + g4 * 4;
            if (jgb + 0 > q0s + r15) s0_ = 0.f;
            if (jgb + 1 > q0s + r15) s1_ = 0.f;
            if (jgb + 2 > q0s + r15) s2_ = 0.f;
            if (jgb + 3 > q0s + r15) s3_ = 0.f;
          }
          uint2 w;
          w.x = (unsigned int)f2b(s0_) | ((unsigned int)f2b(s1_) << 16);
          w.y = (unsigned int)f2b(s2_) | ((unsigned int)f2b(s3_) << 16);
          *(uint2*)(&Ps[hd][r15 * 88 + n * 16 + g4 * 4]) = w;
        }
    }

    if (VAR == 0 || VAR == 2) {
      short8 vf[16];
#pragma unroll
      for (int nd = 0; nd < 8; nd++) {
        vf[nd]     = *(const short8*)(vt + (nd * 2 + 0) * 512);
        vf[8 + nd] = *(const short8*)(vt + (nd * 2 + 1) * 512);
      }
#pragma unroll
      for (int kb = 0; kb < 2; kb++) {
        short8 pa0 = *(const short8*)(&Ps[0][r15 * 88 + kb * 32 + g4 * 8]);
        short8 pa1 = *(const short8*)(&Ps[1][r15 * 88 + kb * 32 + g4 * 8]);
#pragma unroll
        for (int nd = 0; nd < 8; nd++) {
          oacc[0][nd] = __builtin_amdgcn_mfma_f32_16x16x32_bf16(pa0, vf[kb * 8 + nd], oacc[0][nd], 0, 0, 0);
          oacc[1][nd] = __builtin_amdgcn_mfma_f32_16x16x32_bf16(pa1, vf[kb * 8 + nd], oacc[1][nd], 0, 0, 0);
        }
      }
    } else if (VAR == 3) {
#pragma unroll
      for (int nd = 0; nd < 8; nd++) {
        dx ^= *(const short8*)(vt + (nd * 2 + 0) * 512);
        dx ^= *(const short8*)(vt + (nd * 2 + 1) * 512);
      }
    } else if (VAR == 1) {
      fdum += b2f(Ps[0][lane * 2]);  // keep Ps writes alive
    }
  }

  if (VAR == 0) {
#pragma unroll
    for (int hd = 0; hd < 2; hd++) {
      const int hh = hh0 + hd;
      float il[4];
#pragma unroll
      for (int i = 0; i < 4; i++) il[i] = __shfl(lrw[hd], g4 * 4 + i);
#pragma unroll
      for (int i = 0; i < 4; i++) {
        int q = q0s + g4 * 4 + i;
        float inv = 1.0f / il[i];
        const unsigned short* gptr = qg + ((size_t)(b * S_ + q)) * NQG + hh * 256 + 128;
        unsigned short* aptr = ag + ((size_t)(b * S_ + q)) * (H_ * D_) + hh * D_;
#pragma unroll
        for (int nd = 0; nd < 8; nd++) {
          int d = nd * 16 + r15;
          float gt = b2f(gptr[d]);
          float sg = 1.0f / (1.0f + __expf(-gt));
          aptr[d] = f2b(oacc[hd][nd][i] * inv * sg);
        }
      }
    }
  } else {
    float val = fdum + lrw[0] + lrw[1] + mrow[0] + mrow[1];
    if (VAR == 2) {
#pragma unroll
      for (int nd = 0; nd < 8; nd++)
#pragma unroll
        for (int i = 0; i < 4; i++) val += oacc[0][nd][i] + oacc[1][nd][i];
    }
    if (VAR == 3)
      val += (float)(short)(dx[0] ^ dx[1] ^ dx[2] ^ dx[3] ^ dx[4] ^ dx[5] ^ dx[6] ^ dx[7]);
    ag[(size_t)p * 64 + lane] = f2b(val);
  }
}

extern "C" void kernel_launch(void* const* d_in, const int* in_sizes, int n_in,
                              void* d_out, int out_size, void* d_ws, size_t ws_size,
                              hipStream_t stream) {
  const float* h_f   = (const float*)d_in[0];
  const float* cosb  = (const float*)d_in[1];
  const float* sinb  = (const float*)d_in[2];
  const float* prior = (const float*)d_in[4];
  const float* Wq    = (const float*)d_in[5];
  const float* Wk    = (const float*)d_in[6];
  const float* Wv    = (const float*)d_in[7];
  const float* Wo    = (const float*)d_in[8];
  const float* qnw   = (const float*)d_in[9];
  const float* knw   = (const float*)d_in[10];

  char* ws = (char*)d_ws;
  size_t off = 0;
  auto alloc = [&](size_t bytes) { char* p = ws + off; off += (bytes + 255) & ~(size_t)255; return p; };
  unsigned short* hb   = (unsigned short*)alloc((size_t)4096 * 2048 * 2);
  unsigned short* WqT  = (unsigned short*)alloc((size_t)4096 * 2048 * 2);
  unsigned short* WkT  = (unsigned short*)alloc((size_t)256 * 2048 * 2);
  unsigned short* WvT  = (unsigned short*)alloc((size_t)256 * 2048 * 2);
  unsigned short* WoT  = (unsigned short*)alloc((size_t)2048 * 2048 * 2);
  unsigned short* qg   = (unsigned short*)alloc((size_t)4096 * 4096 * 2);
  unsigned short* kraw = (unsigned short*)alloc((size_t)4096 * 256 * 2);
  unsigned short* vraw = (unsigned short*)alloc((size_t)4096 * 256 * 2);
  unsigned short* qTb  = (unsigned short*)alloc((size_t)B_ * H_ * S_ * D_ * 2);
  unsigned short* kF   = (unsigned short*)alloc((size_t)B_ * KV_ * S_ * D_ * 2);
  unsigned short* vF   = (unsigned short*)alloc((size_t)B_ * KV_ * S_ * D_ * 2);
  float* ge    = (float*)alloc((size_t)S_ * 4);
  float* kbias = (float*)alloc((size_t)S_ * 4);
  // Aliasing (sequential stream order): ag reuses hb (dead after projection GEMMs).
  unsigned short* ag = hb;

  dim3 blk(256);
  k_prep<<<dim3(8), blk, 0, stream>>>(prior, ge, kbias);
  k_cvt<<<dim3(4096), blk, 0, stream>>>(h_f, hb, (long)4096 * 2048);
  k_transpose<<<dim3(64, 32), blk, 0, stream>>>(Wq, WqT, 2048, 4096);
  k_transpose<<<dim3(4, 32),  blk, 0, stream>>>(Wk, WkT, 2048, 256);
  k_transpose<<<dim3(4, 32),  blk, 0, stream>>>(Wv, WvT, 2048, 256);
  k_transpose<<<dim3(32, 32), blk, 0, stream>>>(Wo, WoT, 2048, 2048);
  k_gemm_bt<0><<<dim3(32, 32), blk, 0, stream>>>(hb, WqT, qg,   4096, 4096, 2048);
  k_gemm_bt<0><<<dim3(2, 32),  blk, 0, stream>>>(hb, WkT, kraw, 4096, 256,  2048);
  k_gemm_bt<0><<<dim3(2, 32),  blk, 0, stream>>>(hb, WvT, vraw, 4096, 256,  2048);
  k_qkpost<<<dim3(18432), blk, 0, stream>>>(qg, kraw, cosb, sinb, ge, qnw, knw, qTb, kF);
  k_vpost<<<dim3(4096), blk, 0, stream>>>(vraw, ge, vF);
  k_attn<0><<<dim3(2048), dim3(64), 0, stream>>>(qTb, kF, vF, kbias, qg, ag);
  k_gemm_bt<1><<<dim3(16, 32), blk, 0, stream>>>(ag, WoT, d_out, 4096, 2048, 2048);
  // ---- ablation dispatches (d_out already final; write to dead WkT scratch; heavy 256-block subset) ----
  k_attn<1><<<dim3(256), dim3(64), 0, stream>>>(qTb, kF, vF, kbias, qg, WkT);
  k_attn<2><<<dim3(256), dim3(64), 0, stream>>>(qTb, kF, vF, kbias, qg, WkT);
  k_attn<3><<<dim3(256), dim3(64), 0, stream>>>(qTb, kF, vF, kbias, qg, WkT);
}

// Round 8
// 427.870 us; speedup vs baseline: 1.4543x; 1.4543x over previous
//
#include <hip/hip_runtime.h>
#include <hip/hip_bf16.h>
#include <stdint.h>

// Problem constants
#define B_    2
#define S_    2048
#define HID_  2048
#define H_    16
#define KV_   2
#define D_    128
#define ROT_  32
#define NQG   4096   // H*2D
#define NKV   256    // KV*D
#define SCALE_ 0.08838834764831845f  // D^-0.5

typedef __attribute__((ext_vector_type(8))) short  short8;
typedef __attribute__((ext_vector_type(4))) float  floatx4;

__device__ __forceinline__ float b2f(unsigned short u) {
  union { unsigned int i; float f; } v; v.i = ((unsigned int)u) << 16; return v.f;
}
__device__ __forceinline__ unsigned short f2b(float f) {
  union { float f; unsigned int i; } v; v.f = f;
  return (unsigned short)((v.i + 0x7fffu + ((v.i >> 16) & 1u)) >> 16);
}
__device__ __forceinline__ void gload_lds16(const unsigned short* g, unsigned short* l) {
  __builtin_amdgcn_global_load_lds((const __attribute__((address_space(1))) void*)g,
                                   (__attribute__((address_space(3))) void*)l, 16, 0, 0);
}

// ---------------- fp32 -> bf16 elementwise convert (8 elems/thread) ----------------
__global__ __launch_bounds__(256) void k_cvt(const float* __restrict__ in,
                                             unsigned short* __restrict__ out, long n) {
  long i0 = ((long)blockIdx.x * 256 + threadIdx.x) * 8;
  if (i0 >= n) return;
  float4 a = *(const float4*)(in + i0);
  float4 b = *(const float4*)(in + i0 + 4);
  short8 v;
  v[0] = (short)f2b(a.x); v[1] = (short)f2b(a.y);
  v[2] = (short)f2b(a.z); v[3] = (short)f2b(a.w);
  v[4] = (short)f2b(b.x); v[5] = (short)f2b(b.y);
  v[6] = (short)f2b(b.z); v[7] = (short)f2b(b.w);
  *(short8*)(out + i0) = v;
}

// ---------------- prep: gamma/eta + folded key bias ----------------
__global__ __launch_bounds__(256) void k_prep(const float* __restrict__ prior,
                                              float* __restrict__ ge,
                                              float* __restrict__ kbias) {
  int i = blockIdx.x * 256 + threadIdx.x;
  if (i >= S_) return;
  float p  = prior[i];
  float pc = p * (float)S_;
  float g  = 1.0f + 0.1f * (pc - 1.0f);
  g = fminf(fmaxf(g, 0.9f), 1.1f);
  ge[i] = g;
  float cb = fminf(fmaxf(p, -3.0f), 3.0f);
  kbias[i] = cb + logf(1.0f + 0.5f * pc);
}

// ---------------- transpose + convert: out_bf16[C][R] = in_fp32[R][C] ----------------
__global__ __launch_bounds__(256) void k_transpose(const float* __restrict__ in,
                                                   unsigned short* __restrict__ out,
                                                   int R, int C) {
  __shared__ unsigned short tile[64][68];
  int tx = threadIdx.x & 15, ty = threadIdx.x >> 4;
  long c0 = (long)blockIdx.x * 64, r0 = (long)blockIdx.y * 64;
#pragma unroll
  for (int i = 0; i < 4; i++) {
    int row = ty + 16 * i;
    const float* src = in + (r0 + row) * C + c0 + 4 * tx;
    float4 v = *(const float4*)src;
    tile[row][4 * tx + 0] = f2b(v.x);
    tile[row][4 * tx + 1] = f2b(v.y);
    tile[row][4 * tx + 2] = f2b(v.z);
    tile[row][4 * tx + 3] = f2b(v.w);
  }
  __syncthreads();
#pragma unroll
  for (int i = 0; i < 4; i++) {
    int oc = ty + 16 * i;
    ushort4 v;
    v.x = tile[4 * tx + 0][oc];
    v.y = tile[4 * tx + 1][oc];
    v.z = tile[4 * tx + 2][oc];
    v.w = tile[4 * tx + 3][oc];
    *(ushort4*)(out + (c0 + oc) * R + r0 + 4 * tx) = v;
  }
}

// ---------------- GEMM: C[M][N] = A[M][K] @ Bt[N][K]^T  (bf16 in, fp32 acc) ----------------
// global_load_lds(16B) staging, double LDS buffer, one barrier/K-step, XOR-16B swizzle:
// linear LDS dest + inverse-swizzled global source + swizzled fragment read (rule #21).
template <int OUT32>
__global__ __launch_bounds__(256) void k_gemm_bt(const unsigned short* __restrict__ A,
                                                 const unsigned short* __restrict__ Bt,
                                                 void* __restrict__ Cv,
                                                 int M, int N, int K) {
  __shared__ __align__(16) unsigned short As[2][128 * 32];
  __shared__ __align__(16) unsigned short Bs[2][128 * 32];
  const int t    = threadIdx.x;
  const int lane = t & 63;
  const int wv   = t >> 6;
  const int wm   = wv >> 1, wn = wv & 1;
  const long m0  = (long)blockIdx.y * 128;
  const long n0  = (long)blockIdx.x * 128;
  const int r15  = lane & 15, g4 = lane >> 4;

  // staging source (chunk-relative): row = lane>>2, col pre-swizzled so that the linear
  // LDS write (lane*16B) lands the swizzled layout; swz col(shorts) = 8*((lane&3)^((lane>>2)&3))
  const int srow = lane >> 2;
  const int scol = ((lane & 3) ^ ((lane >> 2) & 3)) * 8;
  const unsigned short* sA0 = A  + (m0 + wv * 16 + srow)       * K + scol;
  const unsigned short* sA1 = A  + (m0 + (wv + 4) * 16 + srow) * K + scol;
  const unsigned short* sB0 = Bt + (n0 + wv * 16 + srow)       * K + scol;
  const unsigned short* sB1 = Bt + (n0 + (wv + 4) * 16 + srow) * K + scol;

  floatx4 acc[4][4];
#pragma unroll
  for (int m = 0; m < 4; m++)
#pragma unroll
    for (int n = 0; n < 4; n++) acc[m][n] = (floatx4){0.f, 0.f, 0.f, 0.f};

  // prologue: stage K-step 0 into buffer 0
  gload_lds16(sA0, &As[0][wv * 512]);
  gload_lds16(sA1, &As[0][(wv + 4) * 512]);
  gload_lds16(sB0, &Bs[0][wv * 512]);
  gload_lds16(sB1, &Bs[0][(wv + 4) * 512]);
  __syncthreads();

  const int fcol = (g4 ^ (r15 & 3)) * 8;  // swizzled fragment column (shorts)
  int cur = 0;
  for (int k0 = 0; k0 < K; k0 += 32) {
    if (k0 + 32 < K) {  // prefetch next K-step into the other buffer (stays in flight past reads)
      const int nx = cur ^ 1, ko = k0 + 32;
      gload_lds16(sA0 + ko, &As[nx][wv * 512]);
      gload_lds16(sA1 + ko, &As[nx][(wv + 4) * 512]);
      gload_lds16(sB0 + ko, &Bs[nx][wv * 512]);
      gload_lds16(sB1 + ko, &Bs[nx][(wv + 4) * 512]);
    }
    short8 af[4], bf[4];
#pragma unroll
    for (int m = 0; m < 4; m++)
      af[m] = *(const short8*)(&As[cur][(wm * 64 + m * 16 + r15) * 32 + fcol]);
#pragma unroll
    for (int n = 0; n < 4; n++)
      bf[n] = *(const short8*)(&Bs[cur][(wn * 64 + n * 16 + r15) * 32 + fcol]);
#pragma unroll
    for (int m = 0; m < 4; m++)
#pragma unroll
      for (int n = 0; n < 4; n++)
        acc[m][n] = __builtin_amdgcn_mfma_f32_16x16x32_bf16(af[m], bf[n], acc[m][n], 0, 0, 0);
    __syncthreads();  // drains prefetch (vmcnt) + joins readers before buffer reuse
    cur ^= 1;
  }

#pragma unroll
  for (int m = 0; m < 4; m++) {
    const long rbase = m0 + wm * 64 + m * 16 + g4 * 4;
#pragma unroll
    for (int n = 0; n < 4; n++) {
      const long cidx = n0 + wn * 64 + n * 16 + r15;
#pragma unroll
      for (int i = 0; i < 4; i++) {
        if (OUT32) ((float*)Cv)[(rbase + i) * N + cidx] = acc[m][n][i];
        else ((unsigned short*)Cv)[(rbase + i) * N + cidx] = f2b(acc[m][n][i]);
      }
    }
  }
}

// ---------------- q/k postprocess: RMS + RoPE (+gamma for k); K written in fragment-major kF ----------------
__global__ __launch_bounds__(256) void k_qkpost(const unsigned short* __restrict__ qg,
                                                const unsigned short* __restrict__ kraw,
                                                const float* __restrict__ cosb,
                                                const float* __restrict__ sinb,
                                                const float* __restrict__ ge,
                                                const float* __restrict__ qnw,
                                                const float* __restrict__ knw,
                                                unsigned short* __restrict__ qT,
                                                unsigned short* __restrict__ kF) {
  int wid  = (blockIdx.x * 256 + threadIdx.x) >> 6;
  int lane = threadIdx.x & 63;
  int r    = wid % (H_ + KV_);
  long bs  = wid / (H_ + KV_);
  if (bs >= (long)B_ * S_) return;
  int b = (int)(bs >> 11), s = (int)(bs & 2047);
  int d0 = lane * 2;

  float x0, x1;
  if (r < H_) {
    const unsigned short* src = qg + bs * NQG + r * 256 + d0;
    x0 = b2f(src[0]); x1 = b2f(src[1]);
  } else {
    const unsigned short* src = kraw + bs * NKV + (r - H_) * 128 + d0;
    x0 = b2f(src[0]); x1 = b2f(src[1]);
  }
  float ss = x0 * x0 + x1 * x1;
#pragma unroll
  for (int mask = 1; mask < 64; mask <<= 1) ss += __shfl_xor(ss, mask);
  float rstd = rsqrtf(ss * (1.0f / 128.0f) + 1e-6f);
  float w0, w1;
  if (r < H_) { w0 = qnw[d0]; w1 = qnw[d0 + 1]; }
  else        { w0 = knw[d0]; w1 = knw[d0 + 1]; }
  float xn0 = x0 * rstd * w0, xn1 = x1 * rstd * w1;
  float p0 = __shfl_xor(xn0, 8), p1 = __shfl_xor(xn1, 8);
  float y0 = xn0, y1 = xn1;
  if (lane < 16) {
    float c0 = cosb[bs * ROT_ + d0], c1 = cosb[bs * ROT_ + d0 + 1];
    float s0 = sinb[bs * ROT_ + d0], s1 = sinb[bs * ROT_ + d0 + 1];
    float sgn = (lane < 8) ? -1.0f : 1.0f;
    y0 = xn0 * c0 + sgn * p0 * s0;
    y1 = xn1 * c1 + sgn * p1 * s1;
  }
  if (r < H_) {
    unsigned int pack = (unsigned int)f2b(y0) | ((unsigned int)f2b(y1) << 16);
    *(unsigned int*)(qT + ((long)(b * H_ + r) * S_ + s) * D_ + d0) = pack;
  } else {
    float g = ge[s];
    unsigned int pack = (unsigned int)f2b(y0 * g) | ((unsigned int)f2b(y1 * g) << 16);
    int kvb = r - H_;
    // fragment-major: lane l of fragment (s/16, d/32) holds K[s][d], l = (s&15) + ((d>>3)&3)*16
    size_t off = (size_t)(b * KV_ + kvb) * 262144
               + (size_t)((s >> 4) * 4 + (d0 >> 5)) * 512
               + (size_t)(((s & 15) + (((d0 >> 3) & 3)) * 16)) * 8 + (d0 & 7);
    *(unsigned int*)(kF + off) = pack;
  }
}

// ---------------- v postprocess: scale by eta, write fragment-major vF ----------------
__global__ __launch_bounds__(256) void k_vpost(const unsigned short* __restrict__ vraw,
                                               const float* __restrict__ ge,
                                               unsigned short* __restrict__ vF) {
  int bx  = blockIdx.x;
  int scn = bx & 7, d = (bx >> 3) & 127, kvb = (bx >> 10) & 1, b = bx >> 11;
  int s = scn * 256 + threadIdx.x;
  float v = b2f(vraw[((long)(b * S_ + s)) * NKV + kvb * 128 + d]);
  v *= ge[s];
  // fragment-major: chunk (s/64, d/16, (s/32)&1), lane l = (d&15) + ((s>>3)&3)*16, elem = s&7
  size_t off = (size_t)(b * KV_ + kvb) * 262144
             + (size_t)((s >> 6) * 16 + (d >> 4) * 2 + ((s >> 5) & 1)) * 512
             + (size_t)((d & 15) + ((s >> 3) & 3) * 16) * 8 + (s & 7);
  vF[off] = f2b(v);
}

// ---------------- flash attention: 1 wave, 16 q-rows, 2 heads (shared K/V), fragment-major kF/vF ----------------
__global__ __launch_bounds__(64) void k_attn(const unsigned short* __restrict__ qT,
                                             const unsigned short* __restrict__ kF,
                                             const unsigned short* __restrict__ vF,
                                             const float* __restrict__ kbias,
                                             const unsigned short* __restrict__ qg,
                                             unsigned short* __restrict__ ag) {
  __shared__ __align__(16) unsigned short Ps[2][16 * 88];
  const int lane = threadIdx.x;
  const int r15 = lane & 15, g4 = lane >> 4;
  const int p = blockIdx.x;
  const int xcd = p & 7;
  const int grp = xcd >> 1;                         // (b,kvh): 2 XCDs per group
  const int mem = ((p >> 3) << 1) | (xcd & 1);
  const int hp = mem & 3;                           // head pair
  const int strip = 127 - (mem >> 2);               // heavy q-strips first
  const int b = grp >> 1, kvh = grp & 1;
  const int hh0 = kvh * 8 + hp * 2;
  const int q0s = strip * 16;

  const unsigned short* kFg = kF + (size_t)(b * KV_ + kvh) * 262144;
  const unsigned short* vFg = vF + (size_t)(b * KV_ + kvh) * 262144;

  short8 qf[2][4];
#pragma unroll
  for (int hd = 0; hd < 2; hd++) {
    const unsigned short* qp = qT + ((long)(b * H_ + hh0 + hd) * S_ + q0s + r15) * D_ + g4 * 8;
#pragma unroll
    for (int kb = 0; kb < 4; kb++) qf[hd][kb] = *(const short8*)(qp + kb * 32);
  }

  floatx4 oacc[2][8];
#pragma unroll
  for (int hd = 0; hd < 2; hd++)
#pragma unroll
    for (int nd = 0; nd < 8; nd++) oacc[hd][nd] = (floatx4){0.f, 0.f, 0.f, 0.f};
  float mrow[2] = {-1e30f, -1e30f}, lrw[2] = {0.f, 0.f};

  const int ntiles = (strip >> 2) + 1;
  for (int tile = 0; tile < ntiles; tile++) {
    const int j0 = tile * 64;
    const unsigned short* kt = kFg + (size_t)(j0 >> 4) * 2048 + lane * 8;
    const unsigned short* vt = vFg + (size_t)(j0 >> 6) * 8192 + lane * 8;

    floatx4 sacc[2][4];
#pragma unroll
    for (int hd = 0; hd < 2; hd++)
#pragma unroll
      for (int n = 0; n < 4; n++) sacc[hd][n] = (floatx4){0.f, 0.f, 0.f, 0.f};

#pragma unroll
    for (int n = 0; n < 4; n++) {
      short8 a0 = *(const short8*)(kt + n * 2048);
      short8 a1 = *(const short8*)(kt + n * 2048 + 512);
      short8 a2 = *(const short8*)(kt + n * 2048 + 1024);
      short8 a3 = *(const short8*)(kt + n * 2048 + 1536);
      sacc[0][n] = __builtin_amdgcn_mfma_f32_16x16x32_bf16(a0, qf[0][0], sacc[0][n], 0, 0, 0);
      sacc[0][n] = __builtin_amdgcn_mfma_f32_16x16x32_bf16(a1, qf[0][1], sacc[0][n], 0, 0, 0);
      sacc[0][n] = __builtin_amdgcn_mfma_f32_16x16x32_bf16(a2, qf[0][2], sacc[0][n], 0, 0, 0);
      sacc[0][n] = __builtin_amdgcn_mfma_f32_16x16x32_bf16(a3, qf[0][3], sacc[0][n], 0, 0, 0);
      sacc[1][n] = __builtin_amdgcn_mfma_f32_16x16x32_bf16(a0, qf[1][0], sacc[1][n], 0, 0, 0);
      sacc[1][n] = __builtin_amdgcn_mfma_f32_16x16x32_bf16(a1, qf[1][1], sacc[1][n], 0, 0, 0);
      sacc[1][n] = __builtin_amdgcn_mfma_f32_16x16x32_bf16(a2, qf[1][2], sacc[1][n], 0, 0, 0);
      sacc[1][n] = __builtin_amdgcn_mfma_f32_16x16x32_bf16(a3, qf[1][3], sacc[1][n], 0, 0, 0);
    }

    const bool last = (tile == ntiles - 1);
    float4 kb4[4];
#pragma unroll
    for (int n = 0; n < 4; n++) kb4[n] = *(const float4*)(&kbias[j0 + n * 16 + g4 * 4]);
#pragma unroll
    for (int hd = 0; hd < 2; hd++) {
      float scf[4][4];
#pragma unroll
      for (int n = 0; n < 4; n++)
#pragma unroll
        for (int i = 0; i < 4; i++) {
          float kbv = (i == 0) ? kb4[n].x : (i == 1) ? kb4[n].y : (i == 2) ? kb4[n].z : kb4[n].w;
          float v = sacc[hd][n][i] * SCALE_ + kbv;
          if (last) {
            int jg = j0 + n * 16 + g4 * 4 + i;
            if (jg > q0s + r15) v = -1e30f;
          }
          scf[n][i] = v;
        }
      float pmax = scf[0][0];
#pragma unroll
      for (int n = 0; n < 4; n++)
#pragma unroll
        for (int i = 0; i < 4; i++) pmax = fmaxf(pmax, scf[n][i]);
      pmax = fmaxf(pmax, __shfl_xor(pmax, 16));
      pmax = fmaxf(pmax, __shfl_xor(pmax, 32));
      if (__any(pmax > mrow[hd] + 8.0f)) {
        float mn = fmaxf(mrow[hd], pmax);
        float aq = __expf(mrow[hd] - mn);
        mrow[hd] = mn;
        lrw[hd] *= aq;
        float ai[4];
#pragma unroll
        for (int i = 0; i < 4; i++) ai[i] = __shfl(aq, g4 * 4 + i);
#pragma unroll
        for (int nd = 0; nd < 8; nd++)
#pragma unroll
          for (int i = 0; i < 4; i++) oacc[hd][nd][i] *= ai[i];
      }
      float rsum = 0.f;
#pragma unroll
      for (int n = 0; n < 4; n++)
#pragma unroll
        for (int i = 0; i < 4; i++) {
          float pv = __expf(scf[n][i] - mrow[hd]);
          scf[n][i] = pv;
          rsum += pv;
        }
      rsum += __shfl_xor(rsum, 16);
      rsum += __shfl_xor(rsum, 32);
      lrw[hd] += rsum;
#pragma unroll
      for (int n = 0; n < 4; n++) {
        unsigned int lo = (unsigned int)f2b(scf[n][0]) | ((unsigned int)f2b(scf[n][1]) << 16);
        unsigned int hi = (unsigned int)f2b(scf[n][2]) | ((unsigned int)f2b(scf[n][3]) << 16);
        uint2 w; w.x = lo; w.y = hi;
        *(uint2*)(&Ps[hd][r15 * 88 + n * 16 + g4 * 4]) = w;
      }
    }

    short8 vf[16];
#pragma unroll
    for (int nd = 0; nd < 8; nd++) {
      vf[nd]     = *(const short8*)(vt + (nd * 2 + 0) * 512);
      vf[8 + nd] = *(const short8*)(vt + (nd * 2 + 1) * 512);
    }
#pragma unroll
    for (int kb = 0; kb < 2; kb++) {
      short8 pa0 = *(const short8*)(&Ps[0][r15 * 88 + kb * 32 + g4 * 8]);
      short8 pa1 = *(const short8*)(&Ps[1][r15 * 88 + kb * 32 + g4 * 8]);
#pragma unroll
      for (int nd = 0; nd < 8; nd++) {
        oacc[0][nd] = __builtin_amdgcn_mfma_f32_16x16x32_bf16(pa0, vf[kb * 8 + nd], oacc[0][nd], 0, 0, 0);
        oacc[1][nd] = __builtin_amdgcn_mfma_f32_16x16x32_bf16(pa1, vf[kb * 8 + nd], oacc[1][nd], 0, 0, 0);
      }
    }
  }

#pragma unroll
  for (int hd = 0; hd < 2; hd++) {
    const int hh = hh0 + hd;
    float il[4];
#pragma unroll
    for (int i = 0; i < 4; i++) il[i] = __shfl(lrw[hd], g4 * 4 + i);
#pragma unroll
    for (int i = 0; i < 4; i++) {
      int q = q0s + g4 * 4 + i;
      float inv = 1.0f / il[i];
      const unsigned short* gptr = qg + ((size_t)(b * S_ + q)) * NQG + hh * 256 + 128;
      unsigned short* aptr = ag + ((size_t)(b * S_ + q)) * (H_ * D_) + hh * D_;
#pragma unroll
      for (int nd = 0; nd < 8; nd++) {
        int d = nd * 16 + r15;
        float gt = b2f(gptr[d]);
        float sg = 1.0f / (1.0f + __expf(-gt));
        aptr[d] = f2b(oacc[hd][nd][i] * inv * sg);
      }
    }
  }
}

extern "C" void kernel_launch(void* const* d_in, const int* in_sizes, int n_in,
                              void* d_out, int out_size, void* d_ws, size_t ws_size,
                              hipStream_t stream) {
  const float* h_f   = (const float*)d_in[0];
  const float* cosb  = (const float*)d_in[1];
  const float* sinb  = (const float*)d_in[2];
  const float* prior = (const float*)d_in[4];
  const float* Wq    = (const float*)d_in[5];
  const float* Wk    = (const float*)d_in[6];
  const float* Wv    = (const float*)d_in[7];
  const float* Wo    = (const float*)d_in[8];
  const float* qnw   = (const float*)d_in[9];
  const float* knw   = (const float*)d_in[10];

  char* ws = (char*)d_ws;
  size_t off = 0;
  auto alloc = [&](size_t bytes) { char* p = ws + off; off += (bytes + 255) & ~(size_t)255; return p; };
  unsigned short* hb   = (unsigned short*)alloc((size_t)4096 * 2048 * 2);
  unsigned short* WqT  = (unsigned short*)alloc((size_t)4096 * 2048 * 2);
  unsigned short* WkT  = (unsigned short*)alloc((size_t)256 * 2048 * 2);
  unsigned short* WvT  = (unsigned short*)alloc((size_t)256 * 2048 * 2);
  unsigned short* WoT  = (unsigned short*)alloc((size_t)2048 * 2048 * 2);
  unsigned short* qg   = (unsigned short*)alloc((size_t)4096 * 4096 * 2);
  unsigned short* kraw = (unsigned short*)alloc((size_t)4096 * 256 * 2);
  unsigned short* vraw = (unsigned short*)alloc((size_t)4096 * 256 * 2);
  unsigned short* qTb  = (unsigned short*)alloc((size_t)B_ * H_ * S_ * D_ * 2);
  unsigned short* kF   = (unsigned short*)alloc((size_t)B_ * KV_ * S_ * D_ * 2);
  unsigned short* vF   = (unsigned short*)alloc((size_t)B_ * KV_ * S_ * D_ * 2);
  float* ge    = (float*)alloc((size_t)S_ * 4);
  float* kbias = (float*)alloc((size_t)S_ * 4);
  // Aliasing (sequential stream order): ag reuses hb (dead after projection GEMMs).
  unsigned short* ag = hb;

  dim3 blk(256);
  k_prep<<<dim3(8), blk, 0, stream>>>(prior, ge, kbias);
  k_cvt<<<dim3(4096), blk, 0, stream>>>(h_f, hb, (long)4096 * 2048);
  k_transpose<<<dim3(64, 32), blk, 0, stream>>>(Wq, WqT, 2048, 4096);
  k_transpose<<<dim3(4, 32),  blk, 0, stream>>>(Wk, WkT, 2048, 256);
  k_transpose<<<dim3(4, 32),  blk, 0, stream>>>(Wv, WvT, 2048, 256);
  k_transpose<<<dim3(32, 32), blk, 0, stream>>>(Wo, WoT, 2048, 2048);
  k_gemm_bt<0><<<dim3(32, 32), blk, 0, stream>>>(hb, WqT, qg,   4096, 4096, 2048);
  k_gemm_bt<0><<<dim3(2, 32),  blk, 0, stream>>>(hb, WkT, kraw, 4096, 256,  2048);
  k_gemm_bt<0><<<dim3(2, 32),  blk, 0, stream>>>(hb, WvT, vraw, 4096, 256,  2048);
  k_qkpost<<<dim3(18432), blk, 0, stream>>>(qg, kraw, cosb, sinb, ge, qnw, knw, qTb, kF);
  k_vpost<<<dim3(4096), blk, 0, stream>>>(vraw, ge, vF);
  k_attn<<<dim3(2048), dim3(64), 0, stream>>>(qTb, kF, vF, kbias, qg, ag);
  k_gemm_bt<1><<<dim3(16, 32), blk, 0, stream>>>(ag, WoT, d_out, 4096, 2048, 2048);
}

// Round 9
// 346.643 us; speedup vs baseline: 1.7950x; 1.2343x over previous
//
#include <hip/hip_runtime.h>
#include <hip/hip_bf16.h>
#include <stdint.h>

// Problem constants
#define B_    2
#define S_    2048
#define HID_  2048
#define H_    16
#define KV_   2
#define D_    128
#define ROT_  32
#define NQG   4096   // H*2D
#define SCALE_ 0.08838834764831845f  // D^-0.5

typedef __attribute__((ext_vector_type(8))) short  short8;
typedef __attribute__((ext_vector_type(4))) float  floatx4;

__device__ __forceinline__ float b2f(unsigned short u) {
  union { unsigned int i; float f; } v; v.i = ((unsigned int)u) << 16; return v.f;
}
__device__ __forceinline__ unsigned short f2b(float f) {
  union { float f; unsigned int i; } v; v.f = f;
  return (unsigned short)((v.i + 0x7fffu + ((v.i >> 16) & 1u)) >> 16);
}
__device__ __forceinline__ void gload_lds16(const unsigned short* g, unsigned short* l) {
  __builtin_amdgcn_global_load_lds((const __attribute__((address_space(1))) void*)g,
                                   (__attribute__((address_space(3))) void*)l, 16, 0, 0);
}

// ---------------- fused preprocessing: prep | cvt | 4 weight transposes ----------------
__device__ __forceinline__ void transpose_body(const float* __restrict__ in,
                                               unsigned short* __restrict__ out,
                                               int R, int C, int bx, int by, int t) {
  __shared__ unsigned short tile[64][68];
  int tx = t & 15, ty = t >> 4;
  long c0 = (long)bx * 64, r0 = (long)by * 64;
#pragma unroll
  for (int i = 0; i < 4; i++) {
    int row = ty + 16 * i;
    const float* src = in + (r0 + row) * C + c0 + 4 * tx;
    float4 v = *(const float4*)src;
    tile[row][4 * tx + 0] = f2b(v.x);
    tile[row][4 * tx + 1] = f2b(v.y);
    tile[row][4 * tx + 2] = f2b(v.z);
    tile[row][4 * tx + 3] = f2b(v.w);
  }
  __syncthreads();
#pragma unroll
  for (int i = 0; i < 4; i++) {
    int oc = ty + 16 * i;
    ushort4 v;
    v.x = tile[4 * tx + 0][oc];
    v.y = tile[4 * tx + 1][oc];
    v.z = tile[4 * tx + 2][oc];
    v.w = tile[4 * tx + 3][oc];
    *(ushort4*)(out + (c0 + oc) * R + r0 + 4 * tx) = v;
  }
}

__global__ __launch_bounds__(256) void k_preproc(const float* __restrict__ h_f,
                                                 const float* __restrict__ prior,
                                                 const float* __restrict__ Wq,
                                                 const float* __restrict__ Wk,
                                                 const float* __restrict__ Wv,
                                                 const float* __restrict__ Wo,
                                                 unsigned short* __restrict__ hb,
                                                 unsigned short* __restrict__ WqT,
                                                 unsigned short* __restrict__ WkvT,
                                                 unsigned short* __restrict__ WoT,
                                                 float* __restrict__ ge,
                                                 float* __restrict__ kbias) {
  int bx = blockIdx.x;
  const int t = threadIdx.x;
  if (bx < 8) {  // prep: gamma/eta + folded key bias
    int i = bx * 256 + t;
    float p  = prior[i];
    float pc = p * (float)S_;
    float g  = 1.0f + 0.1f * (pc - 1.0f);
    g = fminf(fmaxf(g, 0.9f), 1.1f);
    ge[i] = g;
    float cb = fminf(fmaxf(p, -3.0f), 3.0f);
    kbias[i] = cb + logf(1.0f + 0.5f * pc);
    return;
  }
  bx -= 8;
  if (bx < 4096) {  // cvt fp32 -> bf16, 8 elems/thread
    long i0 = ((long)bx * 256 + t) * 8;
    float4 a = *(const float4*)(h_f + i0);
    float4 b = *(const float4*)(h_f + i0 + 4);
    short8 v;
    v[0] = (short)f2b(a.x); v[1] = (short)f2b(a.y);
    v[2] = (short)f2b(a.z); v[3] = (short)f2b(a.w);
    v[4] = (short)f2b(b.x); v[5] = (short)f2b(b.y);
    v[6] = (short)f2b(b.z); v[7] = (short)f2b(b.w);
    *(short8*)(hb + i0) = v;
    return;
  }
  bx -= 4096;
  if (bx < 2048) { transpose_body(Wq, WqT, 2048, 4096, bx & 63, bx >> 6, t); return; }
  bx -= 2048;
  if (bx < 1024) { transpose_body(Wo, WoT, 2048, 2048, bx & 31, bx >> 5, t); return; }
  bx -= 1024;
  if (bx < 128)  { transpose_body(Wk, WkvT, 2048, 256, bx & 3, bx >> 2, t); return; }
  bx -= 128;
  transpose_body(Wv, WkvT + (size_t)256 * 2048, 2048, 256, bx & 3, bx >> 2, t);
}

// ---------------- GEMM: C[M][N] = A[M][K] @ Bt[N][K]^T  (bf16 in, fp32 acc) ----------------
// global_load_lds(16B) staging, double LDS buffer, one barrier/K-step, XOR-16B swizzle.
template <int OUT32>
__global__ __launch_bounds__(256) void k_gemm_bt(const unsigned short* __restrict__ A,
                                                 const unsigned short* __restrict__ Bt,
                                                 void* __restrict__ Cv,
                                                 int M, int N, int K) {
  __shared__ __align__(16) unsigned short As[2][128 * 32];
  __shared__ __align__(16) unsigned short Bs[2][128 * 32];
  const int t    = threadIdx.x;
  const int lane = t & 63;
  const int wv   = t >> 6;
  const int wm   = wv >> 1, wn = wv & 1;
  const long m0  = (long)blockIdx.y * 128;
  const long n0  = (long)blockIdx.x * 128;
  const int r15  = lane & 15, g4 = lane >> 4;

  const int srow = lane >> 2;
  const int scol = ((lane & 3) ^ ((lane >> 2) & 3)) * 8;
  const unsigned short* sA0 = A  + (m0 + wv * 16 + srow)       * K + scol;
  const unsigned short* sA1 = A  + (m0 + (wv + 4) * 16 + srow) * K + scol;
  const unsigned short* sB0 = Bt + (n0 + wv * 16 + srow)       * K + scol;
  const unsigned short* sB1 = Bt + (n0 + (wv + 4) * 16 + srow) * K + scol;

  floatx4 acc[4][4];
#pragma unroll
  for (int m = 0; m < 4; m++)
#pragma unroll
    for (int n = 0; n < 4; n++) acc[m][n] = (floatx4){0.f, 0.f, 0.f, 0.f};

  gload_lds16(sA0, &As[0][wv * 512]);
  gload_lds16(sA1, &As[0][(wv + 4) * 512]);
  gload_lds16(sB0, &Bs[0][wv * 512]);
  gload_lds16(sB1, &Bs[0][(wv + 4) * 512]);
  __syncthreads();

  const int fcol = (g4 ^ (r15 & 3)) * 8;
  int cur = 0;
  for (int k0 = 0; k0 < K; k0 += 32) {
    if (k0 + 32 < K) {
      const int nx = cur ^ 1, ko = k0 + 32;
      gload_lds16(sA0 + ko, &As[nx][wv * 512]);
      gload_lds16(sA1 + ko, &As[nx][(wv + 4) * 512]);
      gload_lds16(sB0 + ko, &Bs[nx][wv * 512]);
      gload_lds16(sB1 + ko, &Bs[nx][(wv + 4) * 512]);
    }
    short8 af[4], bf[4];
#pragma unroll
    for (int m = 0; m < 4; m++)
      af[m] = *(const short8*)(&As[cur][(wm * 64 + m * 16 + r15) * 32 + fcol]);
#pragma unroll
    for (int n = 0; n < 4; n++)
      bf[n] = *(const short8*)(&Bs[cur][(wn * 64 + n * 16 + r15) * 32 + fcol]);
#pragma unroll
    for (int m = 0; m < 4; m++)
#pragma unroll
      for (int n = 0; n < 4; n++)
        acc[m][n] = __builtin_amdgcn_mfma_f32_16x16x32_bf16(af[m], bf[n], acc[m][n], 0, 0, 0);
    __syncthreads();
    cur ^= 1;
  }

#pragma unroll
  for (int m = 0; m < 4; m++) {
    const long rbase = m0 + wm * 64 + m * 16 + g4 * 4;
#pragma unroll
    for (int n = 0; n < 4; n++) {
      const long cidx = n0 + wn * 64 + n * 16 + r15;
#pragma unroll
      for (int i = 0; i < 4; i++) {
        if (OUT32) ((float*)Cv)[(rbase + i) * N + cidx] = acc[m][n][i];
        else ((unsigned short*)Cv)[(rbase + i) * N + cidx] = f2b(acc[m][n][i]);
      }
    }
  }
}

// ---------------- fused q/k/v postprocess ----------------
// blocks [0,18432): RMS+RoPE for q (->qT) and k (->fragment-major kF, *gamma)
// blocks [18432, 22528): v scale by eta -> fragment-major vF
__global__ __launch_bounds__(256) void k_qkvpost(const unsigned short* __restrict__ qg,
                                                 const unsigned short* __restrict__ kvraw,
                                                 const float* __restrict__ cosb,
                                                 const float* __restrict__ sinb,
                                                 const float* __restrict__ ge,
                                                 const float* __restrict__ qnw,
                                                 const float* __restrict__ knw,
                                                 unsigned short* __restrict__ qT,
                                                 unsigned short* __restrict__ kF,
                                                 unsigned short* __restrict__ vF) {
  int bxx = blockIdx.x;
  if (bxx < 18432) {
    int wid  = (bxx * 256 + (int)threadIdx.x) >> 6;
    int lane = threadIdx.x & 63;
    int r    = wid % (H_ + KV_);
    long bs  = wid / (H_ + KV_);
    int b = (int)(bs >> 11), s = (int)(bs & 2047);
    int d0 = lane * 2;

    float x0, x1;
    if (r < H_) {
      const unsigned short* src = qg + bs * NQG + r * 256 + d0;
      x0 = b2f(src[0]); x1 = b2f(src[1]);
    } else {
      const unsigned short* src = kvraw + bs * 512 + (r - H_) * 128 + d0;
      x0 = b2f(src[0]); x1 = b2f(src[1]);
    }
    float ss = x0 * x0 + x1 * x1;
#pragma unroll
    for (int mask = 1; mask < 64; mask <<= 1) ss += __shfl_xor(ss, mask);
    float rstd = rsqrtf(ss * (1.0f / 128.0f) + 1e-6f);
    float w0, w1;
    if (r < H_) { w0 = qnw[d0]; w1 = qnw[d0 + 1]; }
    else        { w0 = knw[d0]; w1 = knw[d0 + 1]; }
    float xn0 = x0 * rstd * w0, xn1 = x1 * rstd * w1;
    float p0 = __shfl_xor(xn0, 8), p1 = __shfl_xor(xn1, 8);
    float y0 = xn0, y1 = xn1;
    if (lane < 16) {
      float c0 = cosb[bs * ROT_ + d0], c1 = cosb[bs * ROT_ + d0 + 1];
      float s0 = sinb[bs * ROT_ + d0], s1 = sinb[bs * ROT_ + d0 + 1];
      float sgn = (lane < 8) ? -1.0f : 1.0f;
      y0 = xn0 * c0 + sgn * p0 * s0;
      y1 = xn1 * c1 + sgn * p1 * s1;
    }
    if (r < H_) {
      unsigned int pack = (unsigned int)f2b(y0) | ((unsigned int)f2b(y1) << 16);
      *(unsigned int*)(qT + ((long)(b * H_ + r) * S_ + s) * D_ + d0) = pack;
    } else {
      float g = ge[s];
      unsigned int pack = (unsigned int)f2b(y0 * g) | ((unsigned int)f2b(y1 * g) << 16);
      int kvb = r - H_;
      size_t off = (size_t)(b * KV_ + kvb) * 262144
                 + (size_t)((s >> 4) * 4 + (d0 >> 5)) * 512
                 + (size_t)(((s & 15) + (((d0 >> 3) & 3)) * 16)) * 8 + (d0 & 7);
      *(unsigned int*)(kF + off) = pack;
    }
  } else {
    int bx  = bxx - 18432;
    int scn = bx & 7, d = (bx >> 3) & 127, kvb = (bx >> 10) & 1, b = bx >> 11;
    int s = scn * 256 + threadIdx.x;
    float v = b2f(kvraw[((long)(b * S_ + s)) * 512 + 256 + kvb * 128 + d]);
    v *= ge[s];
    size_t off = (size_t)(b * KV_ + kvb) * 262144
               + (size_t)((s >> 6) * 16 + (d >> 4) * 2 + ((s >> 5) & 1)) * 512
               + (size_t)((d & 15) + ((s >> 3) & 3) * 16) * 8 + (s & 7);
    vF[off] = f2b(v);
  }
}

// ---------------- flash attention: 1 wave, 1 head, 16 q-rows, fragment-major kF/vF ----------------
__global__ __launch_bounds__(64, 4) void k_attn(const unsigned short* __restrict__ qT,
                                                const unsigned short* __restrict__ kF,
                                                const unsigned short* __restrict__ vF,
                                                const float* __restrict__ kbias,
                                                const unsigned short* __restrict__ qg,
                                                unsigned short* __restrict__ ag) {
  __shared__ __align__(16) unsigned short Ps[16 * 88];
  const int lane = threadIdx.x;
  const int r15 = lane & 15, g4 = lane >> 4;
  const int p = blockIdx.x;
  const int xcd = p & 7;
  const int grp = xcd >> 1;                         // (b,kvh): 2 XCDs per group
  const int mem = ((p >> 3) << 1) | (xcd & 1);      // 0..1023 within group
  const int head = mem & 7;
  const int strip = 127 - (mem >> 3);               // heavy q-strips first
  const int b = grp >> 1, kvh = grp & 1;
  const int hh = kvh * 8 + head;
  const int q0s = strip * 16;

  const unsigned short* kFg = kF + (size_t)(b * KV_ + kvh) * 262144;
  const unsigned short* vFg = vF + (size_t)(b * KV_ + kvh) * 262144;

  short8 qf[4];
  {
    const unsigned short* qp = qT + ((long)(b * H_ + hh) * S_ + q0s + r15) * D_ + g4 * 8;
#pragma unroll
    for (int kb = 0; kb < 4; kb++) qf[kb] = *(const short8*)(qp + kb * 32);
  }

  floatx4 oacc[8];
#pragma unroll
  for (int nd = 0; nd < 8; nd++) oacc[nd] = (floatx4){0.f, 0.f, 0.f, 0.f};
  float mrow = -1e30f, lrw = 0.f;

  const int ntiles = (strip >> 2) + 1;
  for (int tile = 0; tile < ntiles; tile++) {
    const int j0 = tile * 64;
    const unsigned short* kt = kFg + (size_t)(j0 >> 4) * 2048 + lane * 8;
    const unsigned short* vt = vFg + (size_t)(j0 >> 6) * 8192 + lane * 8;

    floatx4 sacc[4];
#pragma unroll
    for (int n = 0; n < 4; n++) sacc[n] = (floatx4){0.f, 0.f, 0.f, 0.f};
#pragma unroll
    for (int n = 0; n < 4; n++) {
      short8 a0 = *(const short8*)(kt + n * 2048);
      short8 a1 = *(const short8*)(kt + n * 2048 + 512);
      short8 a2 = *(const short8*)(kt + n * 2048 + 1024);
      short8 a3 = *(const short8*)(kt + n * 2048 + 1536);
      sacc[n] = __builtin_amdgcn_mfma_f32_16x16x32_bf16(a0, qf[0], sacc[n], 0, 0, 0);
      sacc[n] = __builtin_amdgcn_mfma_f32_16x16x32_bf16(a1, qf[1], sacc[n], 0, 0, 0);
      sacc[n] = __builtin_amdgcn_mfma_f32_16x16x32_bf16(a2, qf[2], sacc[n], 0, 0, 0);
      sacc[n] = __builtin_amdgcn_mfma_f32_16x16x32_bf16(a3, qf[3], sacc[n], 0, 0, 0);
    }

    const bool last = (tile == ntiles - 1);
    float scf[4][4];
#pragma unroll
    for (int n = 0; n < 4; n++) {
      float4 kb4 = *(const float4*)(&kbias[j0 + n * 16 + g4 * 4]);
#pragma unroll
      for (int i = 0; i < 4; i++) {
        float kbv = (i == 0) ? kb4.x : (i == 1) ? kb4.y : (i == 2) ? kb4.z : kb4.w;
        float v = sacc[n][i] * SCALE_ + kbv;
        if (last) {
          int jg = j0 + n * 16 + g4 * 4 + i;
          if (jg > q0s + r15) v = -1e30f;
        }
        scf[n][i] = v;
      }
    }
    float pmax = scf[0][0];
#pragma unroll
    for (int n = 0; n < 4; n++)
#pragma unroll
      for (int i = 0; i < 4; i++) pmax = fmaxf(pmax, scf[n][i]);
    pmax = fmaxf(pmax, __shfl_xor(pmax, 16));
    pmax = fmaxf(pmax, __shfl_xor(pmax, 32));
    if (__any(pmax > mrow + 8.0f)) {
      float mn = fmaxf(mrow, pmax);
      float aq = __expf(mrow - mn);
      mrow = mn;
      lrw *= aq;
      float ai[4];
#pragma unroll
      for (int i = 0; i < 4; i++) ai[i] = __shfl(aq, g4 * 4 + i);
#pragma unroll
      for (int nd = 0; nd < 8; nd++)
#pragma unroll
        for (int i = 0; i < 4; i++) oacc[nd][i] *= ai[i];
    }
    float rsum = 0.f;
#pragma unroll
    for (int n = 0; n < 4; n++)
#pragma unroll
      for (int i = 0; i < 4; i++) {
        float pv = __expf(scf[n][i] - mrow);
        scf[n][i] = pv;
        rsum += pv;
      }
    rsum += __shfl_xor(rsum, 16);
    rsum += __shfl_xor(rsum, 32);
    lrw += rsum;

#pragma unroll
    for (int n = 0; n < 4; n++) {
      unsigned int lo = (unsigned int)f2b(scf[n][0]) | ((unsigned int)f2b(scf[n][1]) << 16);
      unsigned int hi = (unsigned int)f2b(scf[n][2]) | ((unsigned int)f2b(scf[n][3]) << 16);
      uint2 w; w.x = lo; w.y = hi;
      *(uint2*)(&Ps[r15 * 88 + n * 16 + g4 * 4]) = w;
    }

#pragma unroll
    for (int kb = 0; kb < 2; kb++) {
      short8 pa = *(const short8*)(&Ps[r15 * 88 + kb * 32 + g4 * 8]);
#pragma unroll
      for (int nd = 0; nd < 8; nd++) {
        short8 bv = *(const short8*)(vt + (nd * 2 + kb) * 512);
        oacc[nd] = __builtin_amdgcn_mfma_f32_16x16x32_bf16(pa, bv, oacc[nd], 0, 0, 0);
      }
    }
  }

  float il[4];
#pragma unroll
  for (int i = 0; i < 4; i++) il[i] = __shfl(lrw, g4 * 4 + i);
#pragma unroll
  for (int i = 0; i < 4; i++) {
    int q = q0s + g4 * 4 + i;
    float inv = 1.0f / il[i];
    const unsigned short* gptr = qg + ((size_t)(b * S_ + q)) * NQG + hh * 256 + 128;
    unsigned short* aptr = ag + ((size_t)(b * S_ + q)) * (H_ * D_) + hh * D_;
#pragma unroll
    for (int nd = 0; nd < 8; nd++) {
      int d = nd * 16 + r15;
      float gt = b2f(gptr[d]);
      float sg = 1.0f / (1.0f + __expf(-gt));
      aptr[d] = f2b(oacc[nd][i] * inv * sg);
    }
  }
}

extern "C" void kernel_launch(void* const* d_in, const int* in_sizes, int n_in,
                              void* d_out, int out_size, void* d_ws, size_t ws_size,
                              hipStream_t stream) {
  const float* h_f   = (const float*)d_in[0];
  const float* cosb  = (const float*)d_in[1];
  const float* sinb  = (const float*)d_in[2];
  const float* prior = (const float*)d_in[4];
  const float* Wq    = (const float*)d_in[5];
  const float* Wk    = (const float*)d_in[6];
  const float* Wv    = (const float*)d_in[7];
  const float* Wo    = (const float*)d_in[8];
  const float* qnw   = (const float*)d_in[9];
  const float* knw   = (const float*)d_in[10];

  char* ws = (char*)d_ws;
  size_t off = 0;
  auto alloc = [&](size_t bytes) { char* p = ws + off; off += (bytes + 255) & ~(size_t)255; return p; };
  unsigned short* hb    = (unsigned short*)alloc((size_t)4096 * 2048 * 2);
  unsigned short* WqT   = (unsigned short*)alloc((size_t)4096 * 2048 * 2);
  unsigned short* WkvT  = (unsigned short*)alloc((size_t)512 * 2048 * 2);
  unsigned short* WoT   = (unsigned short*)alloc((size_t)2048 * 2048 * 2);
  unsigned short* qg    = (unsigned short*)alloc((size_t)4096 * 4096 * 2);
  unsigned short* kvraw = (unsigned short*)alloc((size_t)4096 * 512 * 2);
  unsigned short* qTb   = (unsigned short*)alloc((size_t)B_ * H_ * S_ * D_ * 2);
  unsigned short* kF    = (unsigned short*)alloc((size_t)B_ * KV_ * S_ * D_ * 2);
  unsigned short* vF    = (unsigned short*)alloc((size_t)B_ * KV_ * S_ * D_ * 2);
  float* ge    = (float*)alloc((size_t)S_ * 4);
  float* kbias = (float*)alloc((size_t)S_ * 4);
  // Aliasing (sequential stream order): ag reuses hb (dead after projection GEMMs).
  unsigned short* ag = hb;

  dim3 blk(256);
  k_preproc<<<dim3(7432), blk, 0, stream>>>(h_f, prior, Wq, Wk, Wv, Wo,
                                            hb, WqT, WkvT, WoT, ge, kbias);
  k_gemm_bt<0><<<dim3(32, 32), blk, 0, stream>>>(hb, WqT, qg, 4096, 4096, 2048);
  k_gemm_bt<0><<<dim3(4, 32),  blk, 0, stream>>>(hb, WkvT, kvraw, 4096, 512, 2048);
  k_qkvpost<<<dim3(22528), blk, 0, stream>>>(qg, kvraw, cosb, sinb, ge, qnw, knw, qTb, kF, vF);
  k_attn<<<dim3(4096), dim3(64), 0, stream>>>(qTb, kF, vF, kbias, qg, ag);
  k_gemm_bt<1><<<dim3(16, 32), blk, 0, stream>>>(ag, WoT, d_out, 4096, 2048, 2048);
}

// Round 10
// 294.595 us; speedup vs baseline: 2.1122x; 1.1767x over previous
//
#include <hip/hip_runtime.h>
#include <hip/hip_bf16.h>
#include <stdint.h>

// Problem constants
#define B_    2
#define S_    2048
#define HID_  2048
#define H_    16
#define KV_   2
#define D_    128
#define ROT_  32
#define NQG   4096   // H*2D
#define SCALE_ 0.08838834764831845f  // D^-0.5

typedef __attribute__((ext_vector_type(8))) short  short8;
typedef __attribute__((ext_vector_type(4))) float  floatx4;

__device__ __forceinline__ float b2f(unsigned short u) {
  union { unsigned int i; float f; } v; v.i = ((unsigned int)u) << 16; return v.f;
}
__device__ __forceinline__ unsigned short f2b(float f) {
  union { float f; unsigned int i; } v; v.f = f;
  return (unsigned short)((v.i + 0x7fffu + ((v.i >> 16) & 1u)) >> 16);
}
__device__ __forceinline__ void gload_lds16(const unsigned short* g, unsigned short* l) {
  __builtin_amdgcn_global_load_lds((const __attribute__((address_space(1))) void*)g,
                                   (__attribute__((address_space(3))) void*)l, 16, 0, 0);
}

// ---------------- fused preprocessing: prep | cvt | 4 weight transposes ----------------
__device__ __forceinline__ void transpose_body(const float* __restrict__ in,
                                               unsigned short* __restrict__ out,
                                               int R, int C, int bx, int by, int t) {
  __shared__ unsigned short tile[64][68];
  int tx = t & 15, ty = t >> 4;
  long c0 = (long)bx * 64, r0 = (long)by * 64;
#pragma unroll
  for (int i = 0; i < 4; i++) {
    int row = ty + 16 * i;
    const float* src = in + (r0 + row) * C + c0 + 4 * tx;
    float4 v = *(const float4*)src;
    tile[row][4 * tx + 0] = f2b(v.x);
    tile[row][4 * tx + 1] = f2b(v.y);
    tile[row][4 * tx + 2] = f2b(v.z);
    tile[row][4 * tx + 3] = f2b(v.w);
  }
  __syncthreads();
#pragma unroll
  for (int i = 0; i < 4; i++) {
    int oc = ty + 16 * i;
    ushort4 v;
    v.x = tile[4 * tx + 0][oc];
    v.y = tile[4 * tx + 1][oc];
    v.z = tile[4 * tx + 2][oc];
    v.w = tile[4 * tx + 3][oc];
    *(ushort4*)(out + (c0 + oc) * R + r0 + 4 * tx) = v;
  }
}

__global__ __launch_bounds__(256) void k_preproc(const float* __restrict__ h_f,
                                                 const float* __restrict__ prior,
                                                 const float* __restrict__ Wq,
                                                 const float* __restrict__ Wk,
                                                 const float* __restrict__ Wv,
                                                 const float* __restrict__ Wo,
                                                 unsigned short* __restrict__ hb,
                                                 unsigned short* __restrict__ WqT,
                                                 unsigned short* __restrict__ WkvT,
                                                 unsigned short* __restrict__ WoT,
                                                 float* __restrict__ ge,
                                                 float* __restrict__ kbias) {
  int bx = blockIdx.x;
  const int t = threadIdx.x;
  if (bx < 8) {
    int i = bx * 256 + t;
    float p  = prior[i];
    float pc = p * (float)S_;
    float g  = 1.0f + 0.1f * (pc - 1.0f);
    g = fminf(fmaxf(g, 0.9f), 1.1f);
    ge[i] = g;
    float cb = fminf(fmaxf(p, -3.0f), 3.0f);
    kbias[i] = cb + logf(1.0f + 0.5f * pc);
    return;
  }
  bx -= 8;
  if (bx < 4096) {
    long i0 = ((long)bx * 256 + t) * 8;
    float4 a = *(const float4*)(h_f + i0);
    float4 b = *(const float4*)(h_f + i0 + 4);
    short8 v;
    v[0] = (short)f2b(a.x); v[1] = (short)f2b(a.y);
    v[2] = (short)f2b(a.z); v[3] = (short)f2b(a.w);
    v[4] = (short)f2b(b.x); v[5] = (short)f2b(b.y);
    v[6] = (short)f2b(b.z); v[7] = (short)f2b(b.w);
    *(short8*)(hb + i0) = v;
    return;
  }
  bx -= 4096;
  if (bx < 2048) { transpose_body(Wq, WqT, 2048, 4096, bx & 63, bx >> 6, t); return; }
  bx -= 2048;
  if (bx < 1024) { transpose_body(Wo, WoT, 2048, 2048, bx & 31, bx >> 5, t); return; }
  bx -= 1024;
  if (bx < 128)  { transpose_body(Wk, WkvT, 2048, 256, bx & 3, bx >> 2, t); return; }
  bx -= 128;
  transpose_body(Wv, WkvT + (size_t)256 * 2048, 2048, 256, bx & 3, bx >> 2, t);
}

// ---------------- GEMM: C[M][N] = A[M][K] @ Bt[N][K]^T  (bf16 in, fp32 acc) ----------------
template <int OUT32>
__global__ __launch_bounds__(256) void k_gemm_bt(const unsigned short* __restrict__ A,
                                                 const unsigned short* __restrict__ Bt,
                                                 void* __restrict__ Cv,
                                                 int M, int N, int K) {
  __shared__ __align__(16) unsigned short As[2][128 * 32];
  __shared__ __align__(16) unsigned short Bs[2][128 * 32];
  const int t    = threadIdx.x;
  const int lane = t & 63;
  const int wv   = t >> 6;
  const int wm   = wv >> 1, wn = wv & 1;
  const long m0  = (long)blockIdx.y * 128;
  const long n0  = (long)blockIdx.x * 128;
  const int r15  = lane & 15, g4 = lane >> 4;

  const int srow = lane >> 2;
  const int scol = ((lane & 3) ^ ((lane >> 2) & 3)) * 8;
  const unsigned short* sA0 = A  + (m0 + wv * 16 + srow)       * K + scol;
  const unsigned short* sA1 = A  + (m0 + (wv + 4) * 16 + srow) * K + scol;
  const unsigned short* sB0 = Bt + (n0 + wv * 16 + srow)       * K + scol;
  const unsigned short* sB1 = Bt + (n0 + (wv + 4) * 16 + srow) * K + scol;

  floatx4 acc[4][4];
#pragma unroll
  for (int m = 0; m < 4; m++)
#pragma unroll
    for (int n = 0; n < 4; n++) acc[m][n] = (floatx4){0.f, 0.f, 0.f, 0.f};

  gload_lds16(sA0, &As[0][wv * 512]);
  gload_lds16(sA1, &As[0][(wv + 4) * 512]);
  gload_lds16(sB0, &Bs[0][wv * 512]);
  gload_lds16(sB1, &Bs[0][(wv + 4) * 512]);
  __syncthreads();

  const int fcol = (g4 ^ (r15 & 3)) * 8;
  int cur = 0;
  for (int k0 = 0; k0 < K; k0 += 32) {
    if (k0 + 32 < K) {
      const int nx = cur ^ 1, ko = k0 + 32;
      gload_lds16(sA0 + ko, &As[nx][wv * 512]);
      gload_lds16(sA1 + ko, &As[nx][(wv + 4) * 512]);
      gload_lds16(sB0 + ko, &Bs[nx][wv * 512]);
      gload_lds16(sB1 + ko, &Bs[nx][(wv + 4) * 512]);
    }
    short8 af[4], bf[4];
#pragma unroll
    for (int m = 0; m < 4; m++)
      af[m] = *(const short8*)(&As[cur][(wm * 64 + m * 16 + r15) * 32 + fcol]);
#pragma unroll
    for (int n = 0; n < 4; n++)
      bf[n] = *(const short8*)(&Bs[cur][(wn * 64 + n * 16 + r15) * 32 + fcol]);
#pragma unroll
    for (int m = 0; m < 4; m++)
#pragma unroll
      for (int n = 0; n < 4; n++)
        acc[m][n] = __builtin_amdgcn_mfma_f32_16x16x32_bf16(af[m], bf[n], acc[m][n], 0, 0, 0);
    __syncthreads();
    cur ^= 1;
  }

#pragma unroll
  for (int m = 0; m < 4; m++) {
    const long rbase = m0 + wm * 64 + m * 16 + g4 * 4;
#pragma unroll
    for (int n = 0; n < 4; n++) {
      const long cidx = n0 + wn * 64 + n * 16 + r15;
#pragma unroll
      for (int i = 0; i < 4; i++) {
        if (OUT32) ((float*)Cv)[(rbase + i) * N + cidx] = acc[m][n][i];
        else ((unsigned short*)Cv)[(rbase + i) * N + cidx] = f2b(acc[m][n][i]);
      }
    }
  }
}

// ---------------- fused q/k/v postprocess ----------------
__global__ __launch_bounds__(256) void k_qkvpost(const unsigned short* __restrict__ qg,
                                                 const unsigned short* __restrict__ kvraw,
                                                 const float* __restrict__ cosb,
                                                 const float* __restrict__ sinb,
                                                 const float* __restrict__ ge,
                                                 const float* __restrict__ qnw,
                                                 const float* __restrict__ knw,
                                                 unsigned short* __restrict__ qT,
                                                 unsigned short* __restrict__ kF,
                                                 unsigned short* __restrict__ vF) {
  int bxx = blockIdx.x;
  if (bxx < 18432) {
    int wid  = (bxx * 256 + (int)threadIdx.x) >> 6;
    int lane = threadIdx.x & 63;
    int r    = wid % (H_ + KV_);
    long bs  = wid / (H_ + KV_);
    int b = (int)(bs >> 11), s = (int)(bs & 2047);
    int d0 = lane * 2;

    float x0, x1;
    if (r < H_) {
      const unsigned short* src = qg + bs * NQG + r * 256 + d0;
      x0 = b2f(src[0]); x1 = b2f(src[1]);
    } else {
      const unsigned short* src = kvraw + bs * 512 + (r - H_) * 128 + d0;
      x0 = b2f(src[0]); x1 = b2f(src[1]);
    }
    float ss = x0 * x0 + x1 * x1;
#pragma unroll
    for (int mask = 1; mask < 64; mask <<= 1) ss += __shfl_xor(ss, mask);
    float rstd = rsqrtf(ss * (1.0f / 128.0f) + 1e-6f);
    float w0, w1;
    if (r < H_) { w0 = qnw[d0]; w1 = qnw[d0 + 1]; }
    else        { w0 = knw[d0]; w1 = knw[d0 + 1]; }
    float xn0 = x0 * rstd * w0, xn1 = x1 * rstd * w1;
    float p0 = __shfl_xor(xn0, 8), p1 = __shfl_xor(xn1, 8);
    float y0 = xn0, y1 = xn1;
    if (lane < 16) {
      float c0 = cosb[bs * ROT_ + d0], c1 = cosb[bs * ROT_ + d0 + 1];
      float s0 = sinb[bs * ROT_ + d0], s1 = sinb[bs * ROT_ + d0 + 1];
      float sgn = (lane < 8) ? -1.0f : 1.0f;
      y0 = xn0 * c0 + sgn * p0 * s0;
      y1 = xn1 * c1 + sgn * p1 * s1;
    }
    if (r < H_) {
      unsigned int pack = (unsigned int)f2b(y0) | ((unsigned int)f2b(y1) << 16);
      *(unsigned int*)(qT + ((long)(b * H_ + r) * S_ + s) * D_ + d0) = pack;
    } else {
      float g = ge[s];
      unsigned int pack = (unsigned int)f2b(y0 * g) | ((unsigned int)f2b(y1 * g) << 16);
      int kvb = r - H_;
      size_t off = (size_t)(b * KV_ + kvb) * 262144
                 + (size_t)((s >> 4) * 4 + (d0 >> 5)) * 512
                 + (size_t)(((s & 15) + (((d0 >> 3) & 3)) * 16)) * 8 + (d0 & 7);
      *(unsigned int*)(kF + off) = pack;
    }
  } else {
    int bx  = bxx - 18432;
    int scn = bx & 7, d = (bx >> 3) & 127, kvb = (bx >> 10) & 1, b = bx >> 11;
    int s = scn * 256 + threadIdx.x;
    float v = b2f(kvraw[((long)(b * S_ + s)) * 512 + 256 + kvb * 128 + d]);
    v *= ge[s];
    size_t off = (size_t)(b * KV_ + kvb) * 262144
               + (size_t)((s >> 6) * 16 + (d >> 4) * 2 + ((s >> 5) & 1)) * 512
               + (size_t)((d & 15) + ((s >> 3) & 3) * 16) * 8 + (s & 7);
    vF[off] = f2b(v);
  }
}

// ---------------- flash attention: 256-thr block = 4 waves = 4 strips of ONE head ----------------
// K tile (16 KB, contiguous in fragment-major kF) staged once per block into double-buffered
// LDS via global_load_lds; tile t+1 prefetched during tile t's compute (one barrier per tile).
// V read direct from global (L2-hot, 8-way head reuse), split kb=0 / kb=1 to hide latency.
__global__ __launch_bounds__(256) void k_attn(const unsigned short* __restrict__ qT,
                                              const unsigned short* __restrict__ kF,
                                              const unsigned short* __restrict__ vF,
                                              const float* __restrict__ kbias,
                                              const unsigned short* __restrict__ qg,
                                              unsigned short* __restrict__ ag) {
  __shared__ __align__(16) unsigned short KL[2][8192];   // 2 x 16 KB K tile
  __shared__ __align__(16) unsigned short Ps[4][16 * 88];
  const int t = threadIdx.x;
  const int lane = t & 63, wv = t >> 6;
  const int r15 = lane & 15, g4 = lane >> 4;
  const int p = blockIdx.x;
  const int xcd = p & 7;
  const int grp = xcd >> 1;                          // (b,kvh): 2 XCDs per group
  const int mem = ((p >> 3) << 1) | (xcd & 1);       // 0..255 within group
  const int head = mem & 7;
  const int quad = 31 - (mem >> 3);                  // heavy strip-quads first
  const int b = grp >> 1, kvh = grp & 1;
  const int hh = kvh * 8 + head;
  const int strip = quad * 4 + wv;                   // this wave's strip
  const int q0s = strip * 16;
  const int ntiles = quad + 1;                       // same for all 4 waves (strips 4q..4q+3)

  const unsigned short* kFg = kF + (size_t)(b * KV_ + kvh) * 262144;
  const unsigned short* vFg = vF + (size_t)(b * KV_ + kvh) * 262144;

  short8 qf[4];
  {
    const unsigned short* qp = qT + ((long)(b * H_ + hh) * S_ + q0s + r15) * D_ + g4 * 8;
#pragma unroll
    for (int kb = 0; kb < 4; kb++) qf[kb] = *(const short8*)(qp + kb * 32);
  }

  floatx4 oacc[8];
#pragma unroll
  for (int nd = 0; nd < 8; nd++) oacc[nd] = (floatx4){0.f, 0.f, 0.f, 0.f};
  float mrow = -1e30f, lrw = 0.f;

  // prologue: stage K tile 0 (wave wv stages its 4 KB quarter)
#pragma unroll
  for (int i = 0; i < 4; i++)
    gload_lds16(kFg + (size_t)wv * 2048 + i * 512 + lane * 8, &KL[0][wv * 2048 + i * 512]);
  __syncthreads();

  int cur = 0;
  for (int tile = 0; tile < ntiles; tile++) {
    // prefetch K tile t+1 into the other buffer (in flight across this tile's compute)
    if (tile + 1 < ntiles) {
      const size_t src = (size_t)(tile + 1) * 8192 + wv * 2048 + lane * 8;
#pragma unroll
      for (int i = 0; i < 4; i++)
        gload_lds16(kFg + src + i * 512, &KL[cur ^ 1][wv * 2048 + i * 512]);
    }

    // QK^T from LDS (swapped operands: lane holds q-row r15's keys)
    floatx4 sacc[4];
#pragma unroll
    for (int n = 0; n < 4; n++) sacc[n] = (floatx4){0.f, 0.f, 0.f, 0.f};
#pragma unroll
    for (int n = 0; n < 4; n++) {
      const unsigned short* kl = &KL[cur][n * 2048 + lane * 8];
      short8 a0 = *(const short8*)(kl);
      short8 a1 = *(const short8*)(kl + 512);
      short8 a2 = *(const short8*)(kl + 1024);
      short8 a3 = *(const short8*)(kl + 1536);
      sacc[n] = __builtin_amdgcn_mfma_f32_16x16x32_bf16(a0, qf[0], sacc[n], 0, 0, 0);
      sacc[n] = __builtin_amdgcn_mfma_f32_16x16x32_bf16(a1, qf[1], sacc[n], 0, 0, 0);
      sacc[n] = __builtin_amdgcn_mfma_f32_16x16x32_bf16(a2, qf[2], sacc[n], 0, 0, 0);
      sacc[n] = __builtin_amdgcn_mfma_f32_16x16x32_bf16(a3, qf[3], sacc[n], 0, 0, 0);
    }

    // issue V kb=0 half early (independent of softmax; latency hides under it)
    const unsigned short* vt = vFg + (size_t)tile * 8192 + lane * 8;
    short8 vfA[8];
#pragma unroll
    for (int nd = 0; nd < 8; nd++) vfA[nd] = *(const short8*)(vt + (nd * 2) * 512);

    const bool last = (tile == ntiles - 1);
    float scf[4][4];
#pragma unroll
    for (int n = 0; n < 4; n++) {
      const int j0 = tile * 64;
      float4 kb4 = *(const float4*)(&kbias[j0 + n * 16 + g4 * 4]);
#pragma unroll
      for (int i = 0; i < 4; i++) {
        float kbv = (i == 0) ? kb4.x : (i == 1) ? kb4.y : (i == 2) ? kb4.z : kb4.w;
        float v = sacc[n][i] * SCALE_ + kbv;
        if (last) {
          int jg = j0 + n * 16 + g4 * 4 + i;
          if (jg > q0s + r15) v = -1e30f;
        }
        scf[n][i] = v;
      }
    }
    float pmax = scf[0][0];
#pragma unroll
    for (int n = 0; n < 4; n++)
#pragma unroll
      for (int i = 0; i < 4; i++) pmax = fmaxf(pmax, scf[n][i]);
    pmax = fmaxf(pmax, __shfl_xor(pmax, 16));
    pmax = fmaxf(pmax, __shfl_xor(pmax, 32));
    if (__any(pmax > mrow + 8.0f)) {
      float mn = fmaxf(mrow, pmax);
      float aq = __expf(mrow - mn);
      mrow = mn;
      lrw *= aq;
      float ai[4];
#pragma unroll
      for (int i = 0; i < 4; i++) ai[i] = __shfl(aq, g4 * 4 + i);
#pragma unroll
      for (int nd = 0; nd < 8; nd++)
#pragma unroll
        for (int i = 0; i < 4; i++) oacc[nd][i] *= ai[i];
    }
    float rsum = 0.f;
#pragma unroll
    for (int n = 0; n < 4; n++)
#pragma unroll
      for (int i = 0; i < 4; i++) {
        float pv = __expf(scf[n][i] - mrow);
        scf[n][i] = pv;
        rsum += pv;
      }
    rsum += __shfl_xor(rsum, 16);
    rsum += __shfl_xor(rsum, 32);
    lrw += rsum;

#pragma unroll
    for (int n = 0; n < 4; n++) {
      unsigned int lo = (unsigned int)f2b(scf[n][0]) | ((unsigned int)f2b(scf[n][1]) << 16);
      unsigned int hi = (unsigned int)f2b(scf[n][2]) | ((unsigned int)f2b(scf[n][3]) << 16);
      uint2 w; w.x = lo; w.y = hi;
      *(uint2*)(&Ps[wv][r15 * 88 + n * 16 + g4 * 4]) = w;
    }

    // issue V kb=1 half (hides under kb=0 PV MFMAs)
    short8 vfB[8];
#pragma unroll
    for (int nd = 0; nd < 8; nd++) vfB[nd] = *(const short8*)(vt + (nd * 2 + 1) * 512);

    {
      short8 pa0 = *(const short8*)(&Ps[wv][r15 * 88 + g4 * 8]);
#pragma unroll
      for (int nd = 0; nd < 8; nd++)
        oacc[nd] = __builtin_amdgcn_mfma_f32_16x16x32_bf16(pa0, vfA[nd], oacc[nd], 0, 0, 0);
      short8 pa1 = *(const short8*)(&Ps[wv][r15 * 88 + 32 + g4 * 8]);
#pragma unroll
      for (int nd = 0; nd < 8; nd++)
        oacc[nd] = __builtin_amdgcn_mfma_f32_16x16x32_bf16(pa1, vfB[nd], oacc[nd], 0, 0, 0);
    }
    __syncthreads();  // drains prefetch + joins all waves before buffer swap
    cur ^= 1;
  }

  float il[4];
#pragma unroll
  for (int i = 0; i < 4; i++) il[i] = __shfl(lrw, g4 * 4 + i);
#pragma unroll
  for (int i = 0; i < 4; i++) {
    int q = q0s + g4 * 4 + i;
    float inv = 1.0f / il[i];
    const unsigned short* gptr = qg + ((size_t)(b * S_ + q)) * NQG + hh * 256 + 128;
    unsigned short* aptr = ag + ((size_t)(b * S_ + q)) * (H_ * D_) + hh * D_;
#pragma unroll
    for (int nd = 0; nd < 8; nd++) {
      int d = nd * 16 + r15;
      float gt = b2f(gptr[d]);
      float sg = 1.0f / (1.0f + __expf(-gt));
      aptr[d] = f2b(oacc[nd][i] * inv * sg);
    }
  }
}

extern "C" void kernel_launch(void* const* d_in, const int* in_sizes, int n_in,
                              void* d_out, int out_size, void* d_ws, size_t ws_size,
                              hipStream_t stream) {
  const float* h_f   = (const float*)d_in[0];
  const float* cosb  = (const float*)d_in[1];
  const float* sinb  = (const float*)d_in[2];
  const float* prior = (const float*)d_in[4];
  const float* Wq    = (const float*)d_in[5];
  const float* Wk    = (const float*)d_in[6];
  const float* Wv    = (const float*)d_in[7];
  const float* Wo    = (const float*)d_in[8];
  const float* qnw   = (const float*)d_in[9];
  const float* knw   = (const float*)d_in[10];

  char* ws = (char*)d_ws;
  size_t off = 0;
  auto alloc = [&](size_t bytes) { char* p = ws + off; off += (bytes + 255) & ~(size_t)255; return p; };
  unsigned short* hb    = (unsigned short*)alloc((size_t)4096 * 2048 * 2);
  unsigned short* WqT   = (unsigned short*)alloc((size_t)4096 * 2048 * 2);
  unsigned short* WkvT  = (unsigned short*)alloc((size_t)512 * 2048 * 2);
  unsigned short* WoT   = (unsigned short*)alloc((size_t)2048 * 2048 * 2);
  unsigned short* qg    = (unsigned short*)alloc((size_t)4096 * 4096 * 2);
  unsigned short* kvraw = (unsigned short*)alloc((size_t)4096 * 512 * 2);
  unsigned short* qTb   = (unsigned short*)alloc((size_t)B_ * H_ * S_ * D_ * 2);
  unsigned short* kF    = (unsigned short*)alloc((size_t)B_ * KV_ * S_ * D_ * 2);
  unsigned short* vF    = (unsigned short*)alloc((size_t)B_ * KV_ * S_ * D_ * 2);
  float* ge    = (float*)alloc((size_t)S_ * 4);
  float* kbias = (float*)alloc((size_t)S_ * 4);
  // Aliasing (sequential stream order): ag reuses hb (dead after projection GEMMs).
  unsigned short* ag = hb;

  dim3 blk(256);
  k_preproc<<<dim3(7432), blk, 0, stream>>>(h_f, prior, Wq, Wk, Wv, Wo,
                                            hb, WqT, WkvT, WoT, ge, kbias);
  k_gemm_bt<0><<<dim3(32, 32), blk, 0, stream>>>(hb, WqT, qg, 4096, 4096, 2048);
  k_gemm_bt<0><<<dim3(4, 32),  blk, 0, stream>>>(hb, WkvT, kvraw, 4096, 512, 2048);
  k_qkvpost<<<dim3(22528), blk, 0, stream>>>(qg, kvraw, cosb, sinb, ge, qnw, knw, qTb, kF, vF);
  k_attn<<<dim3(1024), blk, 0, stream>>>(qTb, kF, vF, kbias, qg, ag);
  k_gemm_bt<1><<<dim3(16, 32), blk, 0, stream>>>(ag, WoT, d_out, 4096, 2048, 2048);
}

// Round 11
// 269.448 us; speedup vs baseline: 2.3093x; 1.0933x over previous
//
#include <hip/hip_runtime.h>
#include <hip/hip_bf16.h>
#include <stdint.h>

// Problem constants
#define B_    2
#define S_    2048
#define HID_  2048
#define H_    16
#define KV_   2
#define D_    128
#define ROT_  32
#define QGS   4608   // combined qg|k|v row stride
#define SCALE_ 0.08838834764831845f  // D^-0.5

typedef __attribute__((ext_vector_type(8))) short  short8;
typedef __attribute__((ext_vector_type(4))) float  floatx4;

__device__ __forceinline__ float b2f(unsigned short u) {
  union { unsigned int i; float f; } v; v.i = ((unsigned int)u) << 16; return v.f;
}
__device__ __forceinline__ unsigned short f2b(float f) {
  union { float f; unsigned int i; } v; v.f = f;
  return (unsigned short)((v.i + 0x7fffu + ((v.i >> 16) & 1u)) >> 16);
}
__device__ __forceinline__ void gload_lds16(const unsigned short* g, unsigned short* l) {
  __builtin_amdgcn_global_load_lds((const __attribute__((address_space(1))) void*)g,
                                   (__attribute__((address_space(3))) void*)l, 16, 0, 0);
}

// ---------------- fused preprocessing: prep | cvt | 4 weight transposes ----------------
__device__ __forceinline__ void transpose_body(const float* __restrict__ in,
                                               unsigned short* __restrict__ out,
                                               int R, int C, int bx, int by, int t) {
  __shared__ unsigned short tile[64][68];
  int tx = t & 15, ty = t >> 4;
  long c0 = (long)bx * 64, r0 = (long)by * 64;
#pragma unroll
  for (int i = 0; i < 4; i++) {
    int row = ty + 16 * i;
    const float* src = in + (r0 + row) * C + c0 + 4 * tx;
    float4 v = *(const float4*)src;
    tile[row][4 * tx + 0] = f2b(v.x);
    tile[row][4 * tx + 1] = f2b(v.y);
    tile[row][4 * tx + 2] = f2b(v.z);
    tile[row][4 * tx + 3] = f2b(v.w);
  }
  __syncthreads();
#pragma unroll
  for (int i = 0; i < 4; i++) {
    int oc = ty + 16 * i;
    ushort4 v;
    v.x = tile[4 * tx + 0][oc];
    v.y = tile[4 * tx + 1][oc];
    v.z = tile[4 * tx + 2][oc];
    v.w = tile[4 * tx + 3][oc];
    *(ushort4*)(out + (c0 + oc) * R + r0 + 4 * tx) = v;
  }
}

__global__ __launch_bounds__(256) void k_preproc(const float* __restrict__ h_f,
                                                 const float* __restrict__ prior,
                                                 const float* __restrict__ Wq,
                                                 const float* __restrict__ Wk,
                                                 const float* __restrict__ Wv,
                                                 const float* __restrict__ Wo,
                                                 unsigned short* __restrict__ hb,
                                                 unsigned short* __restrict__ WqkvT,
                                                 unsigned short* __restrict__ WoT,
                                                 float* __restrict__ ge,
                                                 float* __restrict__ kbias) {
  int bx = blockIdx.x;
  const int t = threadIdx.x;
  if (bx < 8) {
    int i = bx * 256 + t;
    float p  = prior[i];
    float pc = p * (float)S_;
    float g  = 1.0f + 0.1f * (pc - 1.0f);
    g = fminf(fmaxf(g, 0.9f), 1.1f);
    ge[i] = g;
    float cb = fminf(fmaxf(p, -3.0f), 3.0f);
    kbias[i] = cb + logf(1.0f + 0.5f * pc);
    return;
  }
  bx -= 8;
  if (bx < 4096) {
    long i0 = ((long)bx * 256 + t) * 8;
    float4 a = *(const float4*)(h_f + i0);
    float4 b = *(const float4*)(h_f + i0 + 4);
    short8 v;
    v[0] = (short)f2b(a.x); v[1] = (short)f2b(a.y);
    v[2] = (short)f2b(a.z); v[3] = (short)f2b(a.w);
    v[4] = (short)f2b(b.x); v[5] = (short)f2b(b.y);
    v[6] = (short)f2b(b.z); v[7] = (short)f2b(b.w);
    *(short8*)(hb + i0) = v;
    return;
  }
  bx -= 4096;
  if (bx < 2048) { transpose_body(Wq, WqkvT, 2048, 4096, bx & 63, bx >> 6, t); return; }
  bx -= 2048;
  if (bx < 1024) { transpose_body(Wo, WoT, 2048, 2048, bx & 31, bx >> 5, t); return; }
  bx -= 1024;
  if (bx < 128)  { transpose_body(Wk, WqkvT + (size_t)4096 * 2048, 2048, 256, bx & 3, bx >> 2, t); return; }
  bx -= 128;
  transpose_body(Wv, WqkvT + (size_t)4352 * 2048, 2048, 256, bx & 3, bx >> 2, t);
}

// ---------------- GEMM: C[M][N] = A[M][K] @ Bt[N][K]^T  (bf16 in, fp32 acc) ----------------
// global_load_lds(16B) staging, double LDS buffer, one barrier/K-step.
// Swizzle (rule #21): linear LDS dest + inverse-swizzled global SOURCE + swizzled read.
// slot(row,cb) = ((row>>1)&3) ^ cb  -> 8 distinct (bankbase,slot) pairs per 16 lanes = 2-way (free).
template <int OUT32>
__global__ __launch_bounds__(256) void k_gemm_bt(const unsigned short* __restrict__ A,
                                                 const unsigned short* __restrict__ Bt,
                                                 void* __restrict__ Cv,
                                                 int M, int N, int K) {
  __shared__ __align__(16) unsigned short As[2][128 * 32];
  __shared__ __align__(16) unsigned short Bs[2][128 * 32];
  const int t    = threadIdx.x;
  const int lane = t & 63;
  const int wv   = t >> 6;
  const int wm   = wv >> 1, wn = wv & 1;
  const long m0  = (long)blockIdx.y * 128;
  const long n0  = (long)blockIdx.x * 128;
  const int r15  = lane & 15, g4 = lane >> 4;

  const int srow = lane >> 2;
  const int scol = ((lane & 3) ^ ((lane >> 3) & 3)) * 8;  // inverse swizzle on global source
  const unsigned short* sA0 = A  + (m0 + wv * 16 + srow)       * K + scol;
  const unsigned short* sA1 = A  + (m0 + (wv + 4) * 16 + srow) * K + scol;
  const unsigned short* sB0 = Bt + (n0 + wv * 16 + srow)       * K + scol;
  const unsigned short* sB1 = Bt + (n0 + (wv + 4) * 16 + srow) * K + scol;

  floatx4 acc[4][4];
#pragma unroll
  for (int m = 0; m < 4; m++)
#pragma unroll
    for (int n = 0; n < 4; n++) acc[m][n] = (floatx4){0.f, 0.f, 0.f, 0.f};

  gload_lds16(sA0, &As[0][wv * 512]);
  gload_lds16(sA1, &As[0][(wv + 4) * 512]);
  gload_lds16(sB0, &Bs[0][wv * 512]);
  gload_lds16(sB1, &Bs[0][(wv + 4) * 512]);
  __syncthreads();

  const int fcol = (g4 ^ ((r15 >> 1) & 3)) * 8;  // swizzled fragment read
  int cur = 0;
  for (int k0 = 0; k0 < K; k0 += 32) {
    if (k0 + 32 < K) {
      const int nx = cur ^ 1, ko = k0 + 32;
      gload_lds16(sA0 + ko, &As[nx][wv * 512]);
      gload_lds16(sA1 + ko, &As[nx][(wv + 4) * 512]);
      gload_lds16(sB0 + ko, &Bs[nx][wv * 512]);
      gload_lds16(sB1 + ko, &Bs[nx][(wv + 4) * 512]);
    }
    short8 af[4], bf[4];
#pragma unroll
    for (int m = 0; m < 4; m++)
      af[m] = *(const short8*)(&As[cur][(wm * 64 + m * 16 + r15) * 32 + fcol]);
#pragma unroll
    for (int n = 0; n < 4; n++)
      bf[n] = *(const short8*)(&Bs[cur][(wn * 64 + n * 16 + r15) * 32 + fcol]);
#pragma unroll
    for (int m = 0; m < 4; m++)
#pragma unroll
      for (int n = 0; n < 4; n++)
        acc[m][n] = __builtin_amdgcn_mfma_f32_16x16x32_bf16(af[m], bf[n], acc[m][n], 0, 0, 0);
    __syncthreads();
    cur ^= 1;
  }

#pragma unroll
  for (int m = 0; m < 4; m++) {
    const long rbase = m0 + wm * 64 + m * 16 + g4 * 4;
#pragma unroll
    for (int n = 0; n < 4; n++) {
      const long cidx = n0 + wn * 64 + n * 16 + r15;
#pragma unroll
      for (int i = 0; i < 4; i++) {
        if (OUT32) ((float*)Cv)[(rbase + i) * N + cidx] = acc[m][n][i];
        else ((unsigned short*)Cv)[(rbase + i) * N + cidx] = f2b(acc[m][n][i]);
      }
    }
  }
}

// ---------------- fused q/k/v postprocess (reads combined qgkv[4096][4608]) ----------------
__global__ __launch_bounds__(256) void k_qkvpost(const unsigned short* __restrict__ qgkv,
                                                 const float* __restrict__ cosb,
                                                 const float* __restrict__ sinb,
                                                 const float* __restrict__ ge,
                                                 const float* __restrict__ qnw,
                                                 const float* __restrict__ knw,
                                                 unsigned short* __restrict__ qT,
                                                 unsigned short* __restrict__ kF,
                                                 unsigned short* __restrict__ vF) {
  int bxx = blockIdx.x;
  if (bxx < 18432) {
    int wid  = (bxx * 256 + (int)threadIdx.x) >> 6;
    int lane = threadIdx.x & 63;
    int r    = wid % (H_ + KV_);
    long bs  = wid / (H_ + KV_);
    int b = (int)(bs >> 11), s = (int)(bs & 2047);
    int d0 = lane * 2;

    float x0, x1;
    if (r < H_) {
      const unsigned short* src = qgkv + bs * QGS + r * 256 + d0;
      x0 = b2f(src[0]); x1 = b2f(src[1]);
    } else {
      const unsigned short* src = qgkv + bs * QGS + 4096 + (r - H_) * 128 + d0;
      x0 = b2f(src[0]); x1 = b2f(src[1]);
    }
    float ss = x0 * x0 + x1 * x1;
#pragma unroll
    for (int mask = 1; mask < 64; mask <<= 1) ss += __shfl_xor(ss, mask);
    float rstd = rsqrtf(ss * (1.0f / 128.0f) + 1e-6f);
    float w0, w1;
    if (r < H_) { w0 = qnw[d0]; w1 = qnw[d0 + 1]; }
    else        { w0 = knw[d0]; w1 = knw[d0 + 1]; }
    float xn0 = x0 * rstd * w0, xn1 = x1 * rstd * w1;
    float p0 = __shfl_xor(xn0, 8), p1 = __shfl_xor(xn1, 8);
    float y0 = xn0, y1 = xn1;
    if (lane < 16) {
      float c0 = cosb[bs * ROT_ + d0], c1 = cosb[bs * ROT_ + d0 + 1];
      float s0 = sinb[bs * ROT_ + d0], s1 = sinb[bs * ROT_ + d0 + 1];
      float sgn = (lane < 8) ? -1.0f : 1.0f;
      y0 = xn0 * c0 + sgn * p0 * s0;
      y1 = xn1 * c1 + sgn * p1 * s1;
    }
    if (r < H_) {
      unsigned int pack = (unsigned int)f2b(y0) | ((unsigned int)f2b(y1) << 16);
      *(unsigned int*)(qT + ((long)(b * H_ + r) * S_ + s) * D_ + d0) = pack;
    } else {
      float g = ge[s];
      unsigned int pack = (unsigned int)f2b(y0 * g) | ((unsigned int)f2b(y1 * g) << 16);
      int kvb = r - H_;
      size_t off = (size_t)(b * KV_ + kvb) * 262144
                 + (size_t)((s >> 4) * 4 + (d0 >> 5)) * 512
                 + (size_t)(((s & 15) + (((d0 >> 3) & 3)) * 16)) * 8 + (d0 & 7);
      *(unsigned int*)(kF + off) = pack;
    }
  } else {
    int bx  = bxx - 18432;
    int scn = bx & 7, d = (bx >> 3) & 127, kvb = (bx >> 10) & 1, b = bx >> 11;
    int s = scn * 256 + threadIdx.x;
    float v = b2f(qgkv[((long)(b * S_ + s)) * QGS + 4352 + kvb * 128 + d]);
    v *= ge[s];
    size_t off = (size_t)(b * KV_ + kvb) * 262144
               + (size_t)((s >> 6) * 16 + (d >> 4) * 2 + ((s >> 5) & 1)) * 512
               + (size_t)((d & 15) + ((s >> 3) & 3) * 16) * 8 + (s & 7);
    vF[off] = f2b(v);
  }
}

// ---------------- flash attention: 256-thr block = 4 waves = 4 strips of ONE head ----------------
__global__ __launch_bounds__(256) void k_attn(const unsigned short* __restrict__ qT,
                                              const unsigned short* __restrict__ kF,
                                              const unsigned short* __restrict__ vF,
                                              const float* __restrict__ kbias,
                                              const unsigned short* __restrict__ qgkv,
                                              unsigned short* __restrict__ ag) {
  __shared__ __align__(16) unsigned short KL[2][8192];   // 2 x 16 KB K tile
  __shared__ __align__(16) unsigned short Ps[4][16 * 88];
  const int t = threadIdx.x;
  const int lane = t & 63, wv = t >> 6;
  const int r15 = lane & 15, g4 = lane >> 4;
  const int p = blockIdx.x;
  const int xcd = p & 7;
  const int grp = xcd >> 1;
  const int mem = ((p >> 3) << 1) | (xcd & 1);
  const int head = mem & 7;
  const int quad = 31 - (mem >> 3);
  const int b = grp >> 1, kvh = grp & 1;
  const int hh = kvh * 8 + head;
  const int strip = quad * 4 + wv;
  const int q0s = strip * 16;
  const int ntiles = quad + 1;

  const unsigned short* kFg = kF + (size_t)(b * KV_ + kvh) * 262144;
  const unsigned short* vFg = vF + (size_t)(b * KV_ + kvh) * 262144;

  short8 qf[4];
  {
    const unsigned short* qp = qT + ((long)(b * H_ + hh) * S_ + q0s + r15) * D_ + g4 * 8;
#pragma unroll
    for (int kb = 0; kb < 4; kb++) qf[kb] = *(const short8*)(qp + kb * 32);
  }

  floatx4 oacc[8];
#pragma unroll
  for (int nd = 0; nd < 8; nd++) oacc[nd] = (floatx4){0.f, 0.f, 0.f, 0.f};
  float mrow = -1e30f, lrw = 0.f;

#pragma unroll
  for (int i = 0; i < 4; i++)
    gload_lds16(kFg + (size_t)wv * 2048 + i * 512 + lane * 8, &KL[0][wv * 2048 + i * 512]);
  __syncthreads();

  int cur = 0;
  for (int tile = 0; tile < ntiles; tile++) {
    if (tile + 1 < ntiles) {
      const size_t src = (size_t)(tile + 1) * 8192 + wv * 2048 + lane * 8;
#pragma unroll
      for (int i = 0; i < 4; i++)
        gload_lds16(kFg + src + i * 512, &KL[cur ^ 1][wv * 2048 + i * 512]);
    }

    floatx4 sacc[4];
#pragma unroll
    for (int n = 0; n < 4; n++) sacc[n] = (floatx4){0.f, 0.f, 0.f, 0.f};
    __builtin_amdgcn_s_setprio(1);
#pragma unroll
    for (int n = 0; n < 4; n++) {
      const unsigned short* kl = &KL[cur][n * 2048 + lane * 8];
      short8 a0 = *(const short8*)(kl);
      short8 a1 = *(const short8*)(kl + 512);
      short8 a2 = *(const short8*)(kl + 1024);
      short8 a3 = *(const short8*)(kl + 1536);
      sacc[n] = __builtin_amdgcn_mfma_f32_16x16x32_bf16(a0, qf[0], sacc[n], 0, 0, 0);
      sacc[n] = __builtin_amdgcn_mfma_f32_16x16x32_bf16(a1, qf[1], sacc[n], 0, 0, 0);
      sacc[n] = __builtin_amdgcn_mfma_f32_16x16x32_bf16(a2, qf[2], sacc[n], 0, 0, 0);
      sacc[n] = __builtin_amdgcn_mfma_f32_16x16x32_bf16(a3, qf[3], sacc[n], 0, 0, 0);
    }
    __builtin_amdgcn_s_setprio(0);

    const unsigned short* vt = vFg + (size_t)tile * 8192 + lane * 8;
    short8 vfA[8];
#pragma unroll
    for (int nd = 0; nd < 8; nd++) vfA[nd] = *(const short8*)(vt + (nd * 2) * 512);

    const bool last = (tile == ntiles - 1);
    float scf[4][4];
#pragma unroll
    for (int n = 0; n < 4; n++) {
      const int j0 = tile * 64;
      float4 kb4 = *(const float4*)(&kbias[j0 + n * 16 + g4 * 4]);
#pragma unroll
      for (int i = 0; i < 4; i++) {
        float kbv = (i == 0) ? kb4.x : (i == 1) ? kb4.y : (i == 2) ? kb4.z : kb4.w;
        float v = sacc[n][i] * SCALE_ + kbv;
        if (last) {
          int jg = j0 + n * 16 + g4 * 4 + i;
          if (jg > q0s + r15) v = -1e30f;
        }
        scf[n][i] = v;
      }
    }
    float pmax = scf[0][0];
#pragma unroll
    for (int n = 0; n < 4; n++)
#pragma unroll
      for (int i = 0; i < 4; i++) pmax = fmaxf(pmax, scf[n][i]);
    pmax = fmaxf(pmax, __shfl_xor(pmax, 16));
    pmax = fmaxf(pmax, __shfl_xor(pmax, 32));
    if (__any(pmax > mrow + 8.0f)) {
      float mn = fmaxf(mrow, pmax);
      float aq = __expf(mrow - mn);
      mrow = mn;
      lrw *= aq;
      float ai[4];
#pragma unroll
      for (int i = 0; i < 4; i++) ai[i] = __shfl(aq, g4 * 4 + i);
#pragma unroll
      for (int nd = 0; nd < 8; nd++)
#pragma unroll
        for (int i = 0; i < 4; i++) oacc[nd][i] *= ai[i];
    }
    float rsum = 0.f;
#pragma unroll
    for (int n = 0; n < 4; n++)
#pragma unroll
      for (int i = 0; i < 4; i++) {
        float pv = __expf(scf[n][i] - mrow);
        scf[n][i] = pv;
        rsum += pv;
      }
    rsum += __shfl_xor(rsum, 16);
    rsum += __shfl_xor(rsum, 32);
    lrw += rsum;

#pragma unroll
    for (int n = 0; n < 4; n++) {
      unsigned int lo = (unsigned int)f2b(scf[n][0]) | ((unsigned int)f2b(scf[n][1]) << 16);
      unsigned int hi = (unsigned int)f2b(scf[n][2]) | ((unsigned int)f2b(scf[n][3]) << 16);
      uint2 w; w.x = lo; w.y = hi;
      *(uint2*)(&Ps[wv][r15 * 88 + n * 16 + g4 * 4]) = w;
    }

    short8 vfB[8];
#pragma unroll
    for (int nd = 0; nd < 8; nd++) vfB[nd] = *(const short8*)(vt + (nd * 2 + 1) * 512);

    {
      __builtin_amdgcn_s_setprio(1);
      short8 pa0 = *(const short8*)(&Ps[wv][r15 * 88 + g4 * 8]);
#pragma unroll
      for (int nd = 0; nd < 8; nd++)
        oacc[nd] = __builtin_amdgcn_mfma_f32_16x16x32_bf16(pa0, vfA[nd], oacc[nd], 0, 0, 0);
      short8 pa1 = *(const short8*)(&Ps[wv][r15 * 88 + 32 + g4 * 8]);
#pragma unroll
      for (int nd = 0; nd < 8; nd++)
        oacc[nd] = __builtin_amdgcn_mfma_f32_16x16x32_bf16(pa1, vfB[nd], oacc[nd], 0, 0, 0);
      __builtin_amdgcn_s_setprio(0);
    }
    __syncthreads();
    cur ^= 1;
  }

  float il[4];
#pragma unroll
  for (int i = 0; i < 4; i++) il[i] = __shfl(lrw, g4 * 4 + i);
#pragma unroll
  for (int i = 0; i < 4; i++) {
    int q = q0s + g4 * 4 + i;
    float inv = 1.0f / il[i];
    const unsigned short* gptr = qgkv + ((size_t)(b * S_ + q)) * QGS + hh * 256 + 128;
    unsigned short* aptr = ag + ((size_t)(b * S_ + q)) * (H_ * D_) + hh * D_;
#pragma unroll
    for (int nd = 0; nd < 8; nd++) {
      int d = nd * 16 + r15;
      float gt = b2f(gptr[d]);
      float sg = 1.0f / (1.0f + __expf(-gt));
      aptr[d] = f2b(oacc[nd][i] * inv * sg);
    }
  }
}

extern "C" void kernel_launch(void* const* d_in, const int* in_sizes, int n_in,
                              void* d_out, int out_size, void* d_ws, size_t ws_size,
                              hipStream_t stream) {
  const float* h_f   = (const float*)d_in[0];
  const float* cosb  = (const float*)d_in[1];
  const float* sinb  = (const float*)d_in[2];
  const float* prior = (const float*)d_in[4];
  const float* Wq    = (const float*)d_in[5];
  const float* Wk    = (const float*)d_in[6];
  const float* Wv    = (const float*)d_in[7];
  const float* Wo    = (const float*)d_in[8];
  const float* qnw   = (const float*)d_in[9];
  const float* knw   = (const float*)d_in[10];

  char* ws = (char*)d_ws;
  size_t off = 0;
  auto alloc = [&](size_t bytes) { char* p = ws + off; off += (bytes + 255) & ~(size_t)255; return p; };
  unsigned short* hb    = (unsigned short*)alloc((size_t)4096 * 2048 * 2);
  unsigned short* WqkvT = (unsigned short*)alloc((size_t)4608 * 2048 * 2);  // Wq|Wk|Wv transposed, contiguous
  unsigned short* WoT   = (unsigned short*)alloc((size_t)2048 * 2048 * 2);
  unsigned short* qgkv  = (unsigned short*)alloc((size_t)4096 * QGS * 2);   // combined qg|k|v
  unsigned short* qTb   = (unsigned short*)alloc((size_t)B_ * H_ * S_ * D_ * 2);
  unsigned short* kF    = (unsigned short*)alloc((size_t)B_ * KV_ * S_ * D_ * 2);
  unsigned short* vF    = (unsigned short*)alloc((size_t)B_ * KV_ * S_ * D_ * 2);
  float* ge    = (float*)alloc((size_t)S_ * 4);
  float* kbias = (float*)alloc((size_t)S_ * 4);
  // Aliasing (sequential stream order): ag reuses hb (dead after the projection GEMM).
  unsigned short* ag = hb;

  dim3 blk(256);
  k_preproc<<<dim3(7432), blk, 0, stream>>>(h_f, prior, Wq, Wk, Wv, Wo,
                                            hb, WqkvT, WoT, ge, kbias);
  k_gemm_bt<0><<<dim3(36, 32), blk, 0, stream>>>(hb, WqkvT, qgkv, 4096, QGS, 2048);
  k_qkvpost<<<dim3(22528), blk, 0, stream>>>(qgkv, cosb, sinb, ge, qnw, knw, qTb, kF, vF);
  k_attn<<<dim3(1024), blk, 0, stream>>>(qTb, kF, vF, kbias, qgkv, ag);
  k_gemm_bt<1><<<dim3(16, 32), blk, 0, stream>>>(ag, WoT, d_out, 4096, 2048, 2048);
}

// Round 12
// 268.602 us; speedup vs baseline: 2.3166x; 1.0031x over previous
//
#include <hip/hip_runtime.h>
#include <hip/hip_bf16.h>
#include <stdint.h>

// Problem constants
#define B_    2
#define S_    2048
#define HID_  2048
#define H_    16
#define KV_   2
#define D_    128
#define ROT_  32
#define QGS   4608   // combined qg|k|v row stride
#define SCALE_ 0.08838834764831845f  // D^-0.5

typedef __attribute__((ext_vector_type(8))) short  short8;
typedef __attribute__((ext_vector_type(4))) float  floatx4;

__device__ __forceinline__ float b2f(unsigned short u) {
  union { unsigned int i; float f; } v; v.i = ((unsigned int)u) << 16; return v.f;
}
__device__ __forceinline__ unsigned short f2b(float f) {
  union { float f; unsigned int i; } v; v.f = f;
  return (unsigned short)((v.i + 0x7fffu + ((v.i >> 16) & 1u)) >> 16);
}
__device__ __forceinline__ void gload_lds16(const unsigned short* g, unsigned short* l) {
  __builtin_amdgcn_global_load_lds((const __attribute__((address_space(1))) void*)g,
                                   (__attribute__((address_space(3))) void*)l, 16, 0, 0);
}

// ---------------- fused preprocessing: prep | cvt | 4 weight transposes ----------------
__device__ __forceinline__ void transpose_body(const float* __restrict__ in,
                                               unsigned short* __restrict__ out,
                                               int R, int C, int bx, int by, int t) {
  __shared__ unsigned short tile[64][68];
  int tx = t & 15, ty = t >> 4;
  long c0 = (long)bx * 64, r0 = (long)by * 64;
#pragma unroll
  for (int i = 0; i < 4; i++) {
    int row = ty + 16 * i;
    const float* src = in + (r0 + row) * C + c0 + 4 * tx;
    float4 v = *(const float4*)src;
    tile[row][4 * tx + 0] = f2b(v.x);
    tile[row][4 * tx + 1] = f2b(v.y);
    tile[row][4 * tx + 2] = f2b(v.z);
    tile[row][4 * tx + 3] = f2b(v.w);
  }
  __syncthreads();
#pragma unroll
  for (int i = 0; i < 4; i++) {
    int oc = ty + 16 * i;
    ushort4 v;
    v.x = tile[4 * tx + 0][oc];
    v.y = tile[4 * tx + 1][oc];
    v.z = tile[4 * tx + 2][oc];
    v.w = tile[4 * tx + 3][oc];
    *(ushort4*)(out + (c0 + oc) * R + r0 + 4 * tx) = v;
  }
}

__global__ __launch_bounds__(256) void k_preproc(const float* __restrict__ h_f,
                                                 const float* __restrict__ prior,
                                                 const float* __restrict__ Wq,
                                                 const float* __restrict__ Wk,
                                                 const float* __restrict__ Wv,
                                                 const float* __restrict__ Wo,
                                                 unsigned short* __restrict__ hb,
                                                 unsigned short* __restrict__ WqkvT,
                                                 unsigned short* __restrict__ WoT,
                                                 float* __restrict__ ge,
                                                 float* __restrict__ kbias) {
  int bx = blockIdx.x;
  const int t = threadIdx.x;
  if (bx < 8) {
    int i = bx * 256 + t;
    float p  = prior[i];
    float pc = p * (float)S_;
    float g  = 1.0f + 0.1f * (pc - 1.0f);
    g = fminf(fmaxf(g, 0.9f), 1.1f);
    ge[i] = g;
    float cb = fminf(fmaxf(p, -3.0f), 3.0f);
    kbias[i] = cb + logf(1.0f + 0.5f * pc);
    return;
  }
  bx -= 8;
  if (bx < 4096) {
    long i0 = ((long)bx * 256 + t) * 8;
    float4 a = *(const float4*)(h_f + i0);
    float4 b = *(const float4*)(h_f + i0 + 4);
    short8 v;
    v[0] = (short)f2b(a.x); v[1] = (short)f2b(a.y);
    v[2] = (short)f2b(a.z); v[3] = (short)f2b(a.w);
    v[4] = (short)f2b(b.x); v[5] = (short)f2b(b.y);
    v[6] = (short)f2b(b.z); v[7] = (short)f2b(b.w);
    *(short8*)(hb + i0) = v;
    return;
  }
  bx -= 4096;
  if (bx < 2048) { transpose_body(Wq, WqkvT, 2048, 4096, bx & 63, bx >> 6, t); return; }
  bx -= 2048;
  if (bx < 1024) { transpose_body(Wo, WoT, 2048, 2048, bx & 31, bx >> 5, t); return; }
  bx -= 1024;
  if (bx < 128)  { transpose_body(Wk, WqkvT + (size_t)4096 * 2048, 2048, 256, bx & 3, bx >> 2, t); return; }
  bx -= 128;
  transpose_body(Wv, WqkvT + (size_t)4352 * 2048, 2048, 256, bx & 3, bx >> 2, t);
}

// ---------------- GEMM: C[M][N] = A[M][K] @ Bt[N][K]^T  (bf16 in, fp32 acc) ----------------
// global_load_lds(16B) staging, double LDS buffer, one barrier/K-step, conflict-free swizzle.
// XCD-chunked bijective block swizzle (T1): each XCD owns contiguous A-panel rows (L2-resident).
template <int OUT32>
__global__ __launch_bounds__(256) void k_gemm_bt(const unsigned short* __restrict__ A,
                                                 const unsigned short* __restrict__ Bt,
                                                 void* __restrict__ Cv,
                                                 int M, int N, int K) {
  __shared__ __align__(16) unsigned short As[2][128 * 32];
  __shared__ __align__(16) unsigned short Bs[2][128 * 32];
  const int t    = threadIdx.x;
  const int lane = t & 63;
  const int wv   = t >> 6;
  const int wm   = wv >> 1, wn = wv & 1;
  // XCD swizzle: nwg divisible by 8 for both launches (1152, 512)
  const int nwg  = gridDim.x * gridDim.y;
  const int orig = blockIdx.y * gridDim.x + blockIdx.x;
  const int wg   = (orig & 7) * (nwg >> 3) + (orig >> 3);
  const int bxx  = wg % gridDim.x, byy = wg / gridDim.x;
  const long m0  = (long)byy * 128;
  const long n0  = (long)bxx * 128;
  const int r15  = lane & 15, g4 = lane >> 4;

  const int srow = lane >> 2;
  const int scol = ((lane & 3) ^ ((lane >> 3) & 3)) * 8;  // inverse swizzle on global source
  const unsigned short* sA0 = A  + (m0 + wv * 16 + srow)       * K + scol;
  const unsigned short* sA1 = A  + (m0 + (wv + 4) * 16 + srow) * K + scol;
  const unsigned short* sB0 = Bt + (n0 + wv * 16 + srow)       * K + scol;
  const unsigned short* sB1 = Bt + (n0 + (wv + 4) * 16 + srow) * K + scol;

  floatx4 acc[4][4];
#pragma unroll
  for (int m = 0; m < 4; m++)
#pragma unroll
    for (int n = 0; n < 4; n++) acc[m][n] = (floatx4){0.f, 0.f, 0.f, 0.f};

  gload_lds16(sA0, &As[0][wv * 512]);
  gload_lds16(sA1, &As[0][(wv + 4) * 512]);
  gload_lds16(sB0, &Bs[0][wv * 512]);
  gload_lds16(sB1, &Bs[0][(wv + 4) * 512]);
  __syncthreads();

  const int fcol = (g4 ^ ((r15 >> 1) & 3)) * 8;  // swizzled fragment read
  int cur = 0;
  for (int k0 = 0; k0 < K; k0 += 32) {
    if (k0 + 32 < K) {
      const int nx = cur ^ 1, ko = k0 + 32;
      gload_lds16(sA0 + ko, &As[nx][wv * 512]);
      gload_lds16(sA1 + ko, &As[nx][(wv + 4) * 512]);
      gload_lds16(sB0 + ko, &Bs[nx][wv * 512]);
      gload_lds16(sB1 + ko, &Bs[nx][(wv + 4) * 512]);
    }
    short8 af[4], bf[4];
#pragma unroll
    for (int m = 0; m < 4; m++)
      af[m] = *(const short8*)(&As[cur][(wm * 64 + m * 16 + r15) * 32 + fcol]);
#pragma unroll
    for (int n = 0; n < 4; n++)
      bf[n] = *(const short8*)(&Bs[cur][(wn * 64 + n * 16 + r15) * 32 + fcol]);
#pragma unroll
    for (int m = 0; m < 4; m++)
#pragma unroll
      for (int n = 0; n < 4; n++)
        acc[m][n] = __builtin_amdgcn_mfma_f32_16x16x32_bf16(af[m], bf[n], acc[m][n], 0, 0, 0);
    __syncthreads();
    cur ^= 1;
  }

#pragma unroll
  for (int m = 0; m < 4; m++) {
    const long rbase = m0 + wm * 64 + m * 16 + g4 * 4;
#pragma unroll
    for (int n = 0; n < 4; n++) {
      const long cidx = n0 + wn * 64 + n * 16 + r15;
#pragma unroll
      for (int i = 0; i < 4; i++) {
        if (OUT32) ((float*)Cv)[(rbase + i) * N + cidx] = acc[m][n][i];
        else ((unsigned short*)Cv)[(rbase + i) * N + cidx] = f2b(acc[m][n][i]);
      }
    }
  }
}

// ---------------- k/v postprocess (q handled inline in attn) ----------------
// blocks [0,2048): k rows RMS+RoPE+gamma -> fragment-major kF (one wave per (b,s,kvb))
// blocks [2048,6144): v scale by eta -> fragment-major vF
__global__ __launch_bounds__(256) void k_qkvpost(const unsigned short* __restrict__ qgkv,
                                                 const float* __restrict__ cosb,
                                                 const float* __restrict__ sinb,
                                                 const float* __restrict__ ge,
                                                 const float* __restrict__ knw,
                                                 unsigned short* __restrict__ kF,
                                                 unsigned short* __restrict__ vF) {
  int bxx = blockIdx.x;
  if (bxx < 2048) {
    int wid  = bxx * 4 + ((int)threadIdx.x >> 6);   // 0..8191 over (b,s,kvb)
    int lane = threadIdx.x & 63;
    int kvb  = wid & 1;
    long bs  = wid >> 1;
    int b = (int)(bs >> 11), s = (int)(bs & 2047);
    int d0 = lane * 2;

    const unsigned short* src = qgkv + bs * QGS + 4096 + kvb * 128 + d0;
    float x0 = b2f(src[0]), x1 = b2f(src[1]);
    float ss = x0 * x0 + x1 * x1;
#pragma unroll
    for (int mask = 1; mask < 64; mask <<= 1) ss += __shfl_xor(ss, mask);
    float rstd = rsqrtf(ss * (1.0f / 128.0f) + 1e-6f);
    float w0 = knw[d0], w1 = knw[d0 + 1];
    float xn0 = x0 * rstd * w0, xn1 = x1 * rstd * w1;
    float p0 = __shfl_xor(xn0, 8), p1 = __shfl_xor(xn1, 8);
    float y0 = xn0, y1 = xn1;
    if (lane < 16) {
      float c0 = cosb[bs * ROT_ + d0], c1 = cosb[bs * ROT_ + d0 + 1];
      float s0 = sinb[bs * ROT_ + d0], s1 = sinb[bs * ROT_ + d0 + 1];
      float sgn = (lane < 8) ? -1.0f : 1.0f;
      y0 = xn0 * c0 + sgn * p0 * s0;
      y1 = xn1 * c1 + sgn * p1 * s1;
    }
    float g = ge[s];
    unsigned int pack = (unsigned int)f2b(y0 * g) | ((unsigned int)f2b(y1 * g) << 16);
    size_t off = (size_t)(b * KV_ + kvb) * 262144
               + (size_t)((s >> 4) * 4 + (d0 >> 5)) * 512
               + (size_t)(((s & 15) + (((d0 >> 3) & 3)) * 16)) * 8 + (d0 & 7);
    *(unsigned int*)(kF + off) = pack;
  } else {
    int bx  = bxx - 2048;
    int scn = bx & 7, d = (bx >> 3) & 127, kvb = (bx >> 10) & 1, b = bx >> 11;
    int s = scn * 256 + threadIdx.x;
    float v = b2f(qgkv[((long)(b * S_ + s)) * QGS + 4352 + kvb * 128 + d]);
    v *= ge[s];
    size_t off = (size_t)(b * KV_ + kvb) * 262144
               + (size_t)((s >> 6) * 16 + (d >> 4) * 2 + ((s >> 5) & 1)) * 512
               + (size_t)((d & 15) + ((s >> 3) & 3) * 16) * 8 + (s & 7);
    vF[off] = f2b(v);
  }
}

// ---------------- flash attention: 256-thr block = 4 waves = 4 strips of ONE head ----------------
// q read directly from qgkv; RMS+RoPE done in-register at block start (same op order as the
// old qkpost -> bitwise-identical qf). K staged double-buffered via global_load_lds.
__global__ __launch_bounds__(256) void k_attn(const unsigned short* __restrict__ qgkv,
                                              const unsigned short* __restrict__ kF,
                                              const unsigned short* __restrict__ vF,
                                              const float* __restrict__ kbias,
                                              const float* __restrict__ cosb,
                                              const float* __restrict__ sinb,
                                              const float* __restrict__ qnw,
                                              unsigned short* __restrict__ ag) {
  __shared__ __align__(16) unsigned short KL[2][8192];   // 2 x 16 KB K tile
  __shared__ __align__(16) unsigned short Ps[4][16 * 88];
  const int t = threadIdx.x;
  const int lane = t & 63, wv = t >> 6;
  const int r15 = lane & 15, g4 = lane >> 4;
  const int p = blockIdx.x;
  const int xcd = p & 7;
  const int grp = xcd >> 1;
  const int mem = ((p >> 3) << 1) | (xcd & 1);
  const int head = mem & 7;
  const int quad = 31 - (mem >> 3);
  const int b = grp >> 1, kvh = grp & 1;
  const int hh = kvh * 8 + head;
  const int strip = quad * 4 + wv;
  const int q0s = strip * 16;
  const int ntiles = quad + 1;

  const unsigned short* kFg = kF + (size_t)(b * KV_ + kvh) * 262144;
  const unsigned short* vFg = vF + (size_t)(b * KV_ + kvh) * 262144;

  // ---- load q row (q0s + r15) and apply RMS norm + RoPE in-register ----
  short8 qf[4];
  {
    const int q = q0s + r15;
    const unsigned short* qp = qgkv + ((size_t)(b * S_) + q) * QGS + hh * 256 + g4 * 8;
    float xn[4][8];
    float ssq = 0.f;
#pragma unroll
    for (int kb = 0; kb < 4; kb++) {
      short8 qr = *(const short8*)(qp + kb * 32);
#pragma unroll
      for (int e = 0; e < 8; e++) {
        float x = b2f((unsigned short)qr[e]);
        xn[kb][e] = x;
        ssq += x * x;
      }
    }
    ssq += __shfl_xor(ssq, 16);
    ssq += __shfl_xor(ssq, 32);
    float rstd = rsqrtf(ssq * (1.0f / 128.0f) + 1e-6f);
#pragma unroll
    for (int kb = 0; kb < 4; kb++) {
      float4 w0 = *(const float4*)(&qnw[kb * 32 + g4 * 8]);
      float4 w1 = *(const float4*)(&qnw[kb * 32 + g4 * 8 + 4]);
      xn[kb][0] *= rstd * w0.x; xn[kb][1] *= rstd * w0.y;
      xn[kb][2] *= rstd * w0.z; xn[kb][3] *= rstd * w0.w;
      xn[kb][4] *= rstd * w1.x; xn[kb][5] *= rstd * w1.y;
      xn[kb][6] *= rstd * w1.z; xn[kb][7] *= rstd * w1.w;
    }
    // RoPE on d = g4*8+e < 32 (kb==0): partner d+-16 lives at lane^32 (g4^2), same e
    {
      const float* cb = cosb + ((size_t)(b * S_) + q) * ROT_ + g4 * 8;
      const float* sb = sinb + ((size_t)(b * S_) + q) * ROT_ + g4 * 8;
      float4 c0 = *(const float4*)(cb), c1 = *(const float4*)(cb + 4);
      float4 s0 = *(const float4*)(sb), s1 = *(const float4*)(sb + 4);
      float cv[8] = {c0.x, c0.y, c0.z, c0.w, c1.x, c1.y, c1.z, c1.w};
      float sv[8] = {s0.x, s0.y, s0.z, s0.w, s1.x, s1.y, s1.z, s1.w};
      float sgn = (g4 < 2) ? -1.0f : 1.0f;
#pragma unroll
      for (int e = 0; e < 8; e++) {
        float part = __shfl_xor(xn[0][e], 32);
        xn[0][e] = xn[0][e] * cv[e] + sgn * part * sv[e];
      }
    }
#pragma unroll
    for (int kb = 0; kb < 4; kb++)
#pragma unroll
      for (int e = 0; e < 8; e++) qf[kb][e] = (short)f2b(xn[kb][e]);
  }

  floatx4 oacc[8];
#pragma unroll
  for (int nd = 0; nd < 8; nd++) oacc[nd] = (floatx4){0.f, 0.f, 0.f, 0.f};
  float mrow = -1e30f, lrw = 0.f;

#pragma unroll
  for (int i = 0; i < 4; i++)
    gload_lds16(kFg + (size_t)wv * 2048 + i * 512 + lane * 8, &KL[0][wv * 2048 + i * 512]);
  __syncthreads();

  int cur = 0;
  for (int tile = 0; tile < ntiles; tile++) {
    if (tile + 1 < ntiles) {
      const size_t src = (size_t)(tile + 1) * 8192 + wv * 2048 + lane * 8;
#pragma unroll
      for (int i = 0; i < 4; i++)
        gload_lds16(kFg + src + i * 512, &KL[cur ^ 1][wv * 2048 + i * 512]);
    }

    floatx4 sacc[4];
#pragma unroll
    for (int n = 0; n < 4; n++) sacc[n] = (floatx4){0.f, 0.f, 0.f, 0.f};
    __builtin_amdgcn_s_setprio(1);
#pragma unroll
    for (int n = 0; n < 4; n++) {
      const unsigned short* kl = &KL[cur][n * 2048 + lane * 8];
      short8 a0 = *(const short8*)(kl);
      short8 a1 = *(const short8*)(kl + 512);
      short8 a2 = *(const short8*)(kl + 1024);
      short8 a3 = *(const short8*)(kl + 1536);
      sacc[n] = __builtin_amdgcn_mfma_f32_16x16x32_bf16(a0, qf[0], sacc[n], 0, 0, 0);
      sacc[n] = __builtin_amdgcn_mfma_f32_16x16x32_bf16(a1, qf[1], sacc[n], 0, 0, 0);
      sacc[n] = __builtin_amdgcn_mfma_f32_16x16x32_bf16(a2, qf[2], sacc[n], 0, 0, 0);
      sacc[n] = __builtin_amdgcn_mfma_f32_16x16x32_bf16(a3, qf[3], sacc[n], 0, 0, 0);
    }
    __builtin_amdgcn_s_setprio(0);

    const unsigned short* vt = vFg + (size_t)tile * 8192 + lane * 8;
    short8 vfA[8];
#pragma unroll
    for (int nd = 0; nd < 8; nd++) vfA[nd] = *(const short8*)(vt + (nd * 2) * 512);

    const bool last = (tile == ntiles - 1);
    float scf[4][4];
#pragma unroll
    for (int n = 0; n < 4; n++) {
      const int j0 = tile * 64;
      float4 kb4 = *(const float4*)(&kbias[j0 + n * 16 + g4 * 4]);
#pragma unroll
      for (int i = 0; i < 4; i++) {
        float kbv = (i == 0) ? kb4.x : (i == 1) ? kb4.y : (i == 2) ? kb4.z : kb4.w;
        float v = sacc[n][i] * SCALE_ + kbv;
        if (last) {
          int jg = j0 + n * 16 + g4 * 4 + i;
          if (jg > q0s + r15) v = -1e30f;
        }
        scf[n][i] = v;
      }
    }
    float pmax = scf[0][0];
#pragma unroll
    for (int n = 0; n < 4; n++)
#pragma unroll
      for (int i = 0; i < 4; i++) pmax = fmaxf(pmax, scf[n][i]);
    pmax = fmaxf(pmax, __shfl_xor(pmax, 16));
    pmax = fmaxf(pmax, __shfl_xor(pmax, 32));
    if (__any(pmax > mrow + 8.0f)) {
      float mn = fmaxf(mrow, pmax);
      float aq = __expf(mrow - mn);
      mrow = mn;
      lrw *= aq;
      float ai[4];
#pragma unroll
      for (int i = 0; i < 4; i++) ai[i] = __shfl(aq, g4 * 4 + i);
#pragma unroll
      for (int nd = 0; nd < 8; nd++)
#pragma unroll
        for (int i = 0; i < 4; i++) oacc[nd][i] *= ai[i];
    }
    float rsum = 0.f;
#pragma unroll
    for (int n = 0; n < 4; n++)
#pragma unroll
      for (int i = 0; i < 4; i++) {
        float pv = __expf(scf[n][i] - mrow);
        scf[n][i] = pv;
        rsum += pv;
      }
    rsum += __shfl_xor(rsum, 16);
    rsum += __shfl_xor(rsum, 32);
    lrw += rsum;

#pragma unroll
    for (int n = 0; n < 4; n++) {
      unsigned int lo = (unsigned int)f2b(scf[n][0]) | ((unsigned int)f2b(scf[n][1]) << 16);
      unsigned int hi = (unsigned int)f2b(scf[n][2]) | ((unsigned int)f2b(scf[n][3]) << 16);
      uint2 w; w.x = lo; w.y = hi;
      *(uint2*)(&Ps[wv][r15 * 88 + n * 16 + g4 * 4]) = w;
    }

    short8 vfB[8];
#pragma unroll
    for (int nd = 0; nd < 8; nd++) vfB[nd] = *(const short8*)(vt + (nd * 2 + 1) * 512);

    {
      __builtin_amdgcn_s_setprio(1);
      short8 pa0 = *(const short8*)(&Ps[wv][r15 * 88 + g4 * 8]);
#pragma unroll
      for (int nd = 0; nd < 8; nd++)
        oacc[nd] = __builtin_amdgcn_mfma_f32_16x16x32_bf16(pa0, vfA[nd], oacc[nd], 0, 0, 0);
      short8 pa1 = *(const short8*)(&Ps[wv][r15 * 88 + 32 + g4 * 8]);
#pragma unroll
      for (int nd = 0; nd < 8; nd++)
        oacc[nd] = __builtin_amdgcn_mfma_f32_16x16x32_bf16(pa1, vfB[nd], oacc[nd], 0, 0, 0);
      __builtin_amdgcn_s_setprio(0);
    }
    __syncthreads();
    cur ^= 1;
  }

  float il[4];
#pragma unroll
  for (int i = 0; i < 4; i++) il[i] = __shfl(lrw, g4 * 4 + i);
#pragma unroll
  for (int i = 0; i < 4; i++) {
    int q = q0s + g4 * 4 + i;
    float inv = 1.0f / il[i];
    const unsigned short* gptr = qgkv + ((size_t)(b * S_ + q)) * QGS + hh * 256 + 128;
    unsigned short* aptr = ag + ((size_t)(b * S_ + q)) * (H_ * D_) + hh * D_;
#pragma unroll
    for (int nd = 0; nd < 8; nd++) {
      int d = nd * 16 + r15;
      float gt = b2f(gptr[d]);
      float sg = 1.0f / (1.0f + __expf(-gt));
      aptr[d] = f2b(oacc[nd][i] * inv * sg);
    }
  }
}

extern "C" void kernel_launch(void* const* d_in, const int* in_sizes, int n_in,
                              void* d_out, int out_size, void* d_ws, size_t ws_size,
                              hipStream_t stream) {
  const float* h_f   = (const float*)d_in[0];
  const float* cosb  = (const float*)d_in[1];
  const float* sinb  = (const float*)d_in[2];
  const float* prior = (const float*)d_in[4];
  const float* Wq    = (const float*)d_in[5];
  const float* Wk    = (const float*)d_in[6];
  const float* Wv    = (const float*)d_in[7];
  const float* Wo    = (const float*)d_in[8];
  const float* qnw   = (const float*)d_in[9];
  const float* knw   = (const float*)d_in[10];

  char* ws = (char*)d_ws;
  size_t off = 0;
  auto alloc = [&](size_t bytes) { char* p = ws + off; off += (bytes + 255) & ~(size_t)255; return p; };
  unsigned short* hb    = (unsigned short*)alloc((size_t)4096 * 2048 * 2);
  unsigned short* WqkvT = (unsigned short*)alloc((size_t)4608 * 2048 * 2);  // Wq|Wk|Wv transposed
  unsigned short* WoT   = (unsigned short*)alloc((size_t)2048 * 2048 * 2);
  unsigned short* qgkv  = (unsigned short*)alloc((size_t)4096 * QGS * 2);   // combined qg|k|v
  unsigned short* kF    = (unsigned short*)alloc((size_t)B_ * KV_ * S_ * D_ * 2);
  unsigned short* vF    = (unsigned short*)alloc((size_t)B_ * KV_ * S_ * D_ * 2);
  float* ge    = (float*)alloc((size_t)S_ * 4);
  float* kbias = (float*)alloc((size_t)S_ * 4);
  // Aliasing (sequential stream order): ag reuses hb (dead after the projection GEMM).
  unsigned short* ag = hb;

  dim3 blk(256);
  k_preproc<<<dim3(7432), blk, 0, stream>>>(h_f, prior, Wq, Wk, Wv, Wo,
                                            hb, WqkvT, WoT, ge, kbias);
  k_gemm_bt<0><<<dim3(36, 32), blk, 0, stream>>>(hb, WqkvT, qgkv, 4096, QGS, 2048);
  k_qkvpost<<<dim3(6144), blk, 0, stream>>>(qgkv, cosb, sinb, ge, knw, kF, vF);
  k_attn<<<dim3(1024), blk, 0, stream>>>(qgkv, kF, vF, kbias, cosb, sinb, qnw, ag);
  k_gemm_bt<1><<<dim3(16, 32), blk, 0, stream>>>(ag, WoT, d_out, 4096, 2048, 2048);
}

// Round 13
// 260.559 us; speedup vs baseline: 2.3881x; 1.0309x over previous
//
#include <hip/hip_runtime.h>
#include <hip/hip_bf16.h>
#include <stdint.h>

// Problem constants
#define B_    2
#define S_    2048
#define HID_  2048
#define H_    16
#define KV_   2
#define D_    128
#define ROT_  32
#define QGS   4608   // combined qg|k|v row stride
#define SCALE_ 0.08838834764831845f  // D^-0.5

typedef __attribute__((ext_vector_type(8))) short  short8;
typedef __attribute__((ext_vector_type(4))) float  floatx4;

__device__ __forceinline__ float b2f(unsigned short u) {
  union { unsigned int i; float f; } v; v.i = ((unsigned int)u) << 16; return v.f;
}
__device__ __forceinline__ unsigned short f2b(float f) {
  union { float f; unsigned int i; } v; v.f = f;
  return (unsigned short)((v.i + 0x7fffu + ((v.i >> 16) & 1u)) >> 16);
}
__device__ __forceinline__ void gload_lds16(const unsigned short* g, unsigned short* l) {
  __builtin_amdgcn_global_load_lds((const __attribute__((address_space(1))) void*)g,
                                   (__attribute__((address_space(3))) void*)l, 16, 0, 0);
}

// ---------------- fused preprocessing: prep | cvt | 4 weight transposes ----------------
__device__ __forceinline__ void transpose_body(const float* __restrict__ in,
                                               unsigned short* __restrict__ out,
                                               int R, int C, int bx, int by, int t) {
  __shared__ unsigned short tile[64][68];
  int tx = t & 15, ty = t >> 4;
  long c0 = (long)bx * 64, r0 = (long)by * 64;
#pragma unroll
  for (int i = 0; i < 4; i++) {
    int row = ty + 16 * i;
    const float* src = in + (r0 + row) * C + c0 + 4 * tx;
    float4 v = *(const float4*)src;
    tile[row][4 * tx + 0] = f2b(v.x);
    tile[row][4 * tx + 1] = f2b(v.y);
    tile[row][4 * tx + 2] = f2b(v.z);
    tile[row][4 * tx + 3] = f2b(v.w);
  }
  __syncthreads();
#pragma unroll
  for (int i = 0; i < 4; i++) {
    int oc = ty + 16 * i;
    ushort4 v;
    v.x = tile[4 * tx + 0][oc];
    v.y = tile[4 * tx + 1][oc];
    v.z = tile[4 * tx + 2][oc];
    v.w = tile[4 * tx + 3][oc];
    *(ushort4*)(out + (c0 + oc) * R + r0 + 4 * tx) = v;
  }
}

__global__ __launch_bounds__(256) void k_preproc(const float* __restrict__ h_f,
                                                 const float* __restrict__ prior,
                                                 const float* __restrict__ Wq,
                                                 const float* __restrict__ Wk,
                                                 const float* __restrict__ Wv,
                                                 const float* __restrict__ Wo,
                                                 unsigned short* __restrict__ hb,
                                                 unsigned short* __restrict__ WqkvT,
                                                 unsigned short* __restrict__ WoT,
                                                 float* __restrict__ ge,
                                                 float* __restrict__ kbias) {
  int bx = blockIdx.x;
  const int t = threadIdx.x;
  if (bx < 8) {
    int i = bx * 256 + t;
    float p  = prior[i];
    float pc = p * (float)S_;
    float g  = 1.0f + 0.1f * (pc - 1.0f);
    g = fminf(fmaxf(g, 0.9f), 1.1f);
    ge[i] = g;
    float cb = fminf(fmaxf(p, -3.0f), 3.0f);
    kbias[i] = cb + logf(1.0f + 0.5f * pc);
    return;
  }
  bx -= 8;
  if (bx < 4096) {
    long i0 = ((long)bx * 256 + t) * 8;
    float4 a = *(const float4*)(h_f + i0);
    float4 b = *(const float4*)(h_f + i0 + 4);
    short8 v;
    v[0] = (short)f2b(a.x); v[1] = (short)f2b(a.y);
    v[2] = (short)f2b(a.z); v[3] = (short)f2b(a.w);
    v[4] = (short)f2b(b.x); v[5] = (short)f2b(b.y);
    v[6] = (short)f2b(b.z); v[7] = (short)f2b(b.w);
    *(short8*)(hb + i0) = v;
    return;
  }
  bx -= 4096;
  if (bx < 2048) { transpose_body(Wq, WqkvT, 2048, 4096, bx & 63, bx >> 6, t); return; }
  bx -= 2048;
  if (bx < 1024) { transpose_body(Wo, WoT, 2048, 2048, bx & 31, bx >> 5, t); return; }
  bx -= 1024;
  if (bx < 128)  { transpose_body(Wk, WqkvT + (size_t)4096 * 2048, 2048, 256, bx & 3, bx >> 2, t); return; }
  bx -= 128;
  transpose_body(Wv, WqkvT + (size_t)4352 * 2048, 2048, 256, bx & 3, bx >> 2, t);
}

// ---------------- GEMM: C[M][N] = A[M][K] @ Bt[N][K]^T  (bf16 in, fp32 acc) ----------------
// Counted-vmcnt 2-deep pipeline (T4): 3 LDS buffers, loads for tile k+1 stay in flight
// across the barrier (s_waitcnt vmcnt(4), never 0 in the main loop). One raw s_barrier/K-step.
template <int OUT32>
__global__ __launch_bounds__(256) void k_gemm_bt(const unsigned short* __restrict__ A,
                                                 const unsigned short* __restrict__ Bt,
                                                 void* __restrict__ Cv,
                                                 int M, int N, int K) {
  __shared__ __align__(16) unsigned short As[3][128 * 32];
  __shared__ __align__(16) unsigned short Bs[3][128 * 32];
  const int t    = threadIdx.x;
  const int lane = t & 63;
  const int wv   = t >> 6;
  const int wm   = wv >> 1, wn = wv & 1;
  const long m0  = (long)blockIdx.y * 128;
  const long n0  = (long)blockIdx.x * 128;
  const int r15  = lane & 15, g4 = lane >> 4;

  const int srow = lane >> 2;
  const int scol = ((lane & 3) ^ ((lane >> 3) & 3)) * 8;  // inverse swizzle on global source
  const unsigned short* sA0 = A  + (m0 + wv * 16 + srow)       * K + scol;
  const unsigned short* sA1 = A  + (m0 + (wv + 4) * 16 + srow) * K + scol;
  const unsigned short* sB0 = Bt + (n0 + wv * 16 + srow)       * K + scol;
  const unsigned short* sB1 = Bt + (n0 + (wv + 4) * 16 + srow) * K + scol;

  floatx4 acc[4][4];
#pragma unroll
  for (int m = 0; m < 4; m++)
#pragma unroll
    for (int n = 0; n < 4; n++) acc[m][n] = (floatx4){0.f, 0.f, 0.f, 0.f};

  const int nk = K >> 5;
  // prologue: issue tiles 0 and 1 (4 vmem ops per tile per wave, program order defines vmcnt)
#pragma unroll
  for (int kt = 0; kt < 2; kt++) {
    const int ko = kt * 32;
    gload_lds16(sA0 + ko, &As[kt][wv * 512]);
    gload_lds16(sA1 + ko, &As[kt][(wv + 4) * 512]);
    gload_lds16(sB0 + ko, &Bs[kt][wv * 512]);
    gload_lds16(sB1 + ko, &Bs[kt][(wv + 4) * 512]);
  }

  const int fcol = (g4 ^ ((r15 >> 1) & 3)) * 8;  // swizzled fragment read
  int cb = 0;   // current buffer = k % 3
  for (int k = 0; k < nk; ++k) {
    // wait for tile k's loads (leave tile k+1's 4 in flight), then block-sync
    if (k < nk - 1) asm volatile("s_waitcnt vmcnt(4)" ::: "memory");
    else            asm volatile("s_waitcnt vmcnt(0)" ::: "memory");
    __builtin_amdgcn_sched_barrier(0);
    __builtin_amdgcn_s_barrier();
    __builtin_amdgcn_sched_barrier(0);
    // issue tile k+2 into buffer (k+2)%3 (read last at iter k-1; safe after this barrier)
    if (k + 2 < nk) {
      const int nb = (cb + 2 >= 3) ? cb - 1 : cb + 2;
      const int ko = (k + 2) * 32;
      gload_lds16(sA0 + ko, &As[nb][wv * 512]);
      gload_lds16(sA1 + ko, &As[nb][(wv + 4) * 512]);
      gload_lds16(sB0 + ko, &Bs[nb][wv * 512]);
      gload_lds16(sB1 + ko, &Bs[nb][(wv + 4) * 512]);
    }
    short8 af[4], bf[4];
#pragma unroll
    for (int m = 0; m < 4; m++)
      af[m] = *(const short8*)(&As[cb][(wm * 64 + m * 16 + r15) * 32 + fcol]);
#pragma unroll
    for (int n = 0; n < 4; n++)
      bf[n] = *(const short8*)(&Bs[cb][(wn * 64 + n * 16 + r15) * 32 + fcol]);
#pragma unroll
    for (int m = 0; m < 4; m++)
#pragma unroll
      for (int n = 0; n < 4; n++)
        acc[m][n] = __builtin_amdgcn_mfma_f32_16x16x32_bf16(af[m], bf[n], acc[m][n], 0, 0, 0);
    cb = (cb == 2) ? 0 : cb + 1;
  }

#pragma unroll
  for (int m = 0; m < 4; m++) {
    const long rbase = m0 + wm * 64 + m * 16 + g4 * 4;
#pragma unroll
    for (int n = 0; n < 4; n++) {
      const long cidx = n0 + wn * 64 + n * 16 + r15;
#pragma unroll
      for (int i = 0; i < 4; i++) {
        if (OUT32) ((float*)Cv)[(rbase + i) * N + cidx] = acc[m][n][i];
        else ((unsigned short*)Cv)[(rbase + i) * N + cidx] = f2b(acc[m][n][i]);
      }
    }
  }
}

// ---------------- k/v postprocess (q handled inline in attn) ----------------
__global__ __launch_bounds__(256) void k_qkvpost(const unsigned short* __restrict__ qgkv,
                                                 const float* __restrict__ cosb,
                                                 const float* __restrict__ sinb,
                                                 const float* __restrict__ ge,
                                                 const float* __restrict__ knw,
                                                 unsigned short* __restrict__ kF,
                                                 unsigned short* __restrict__ vF) {
  int bxx = blockIdx.x;
  if (bxx < 2048) {
    int wid  = bxx * 4 + ((int)threadIdx.x >> 6);   // 0..8191 over (b,s,kvb)
    int lane = threadIdx.x & 63;
    int kvb  = wid & 1;
    long bs  = wid >> 1;
    int b = (int)(bs >> 11), s = (int)(bs & 2047);
    int d0 = lane * 2;

    const unsigned short* src = qgkv + bs * QGS + 4096 + kvb * 128 + d0;
    float x0 = b2f(src[0]), x1 = b2f(src[1]);
    float ss = x0 * x0 + x1 * x1;
#pragma unroll
    for (int mask = 1; mask < 64; mask <<= 1) ss += __shfl_xor(ss, mask);
    float rstd = rsqrtf(ss * (1.0f / 128.0f) + 1e-6f);
    float w0 = knw[d0], w1 = knw[d0 + 1];
    float xn0 = x0 * rstd * w0, xn1 = x1 * rstd * w1;
    float p0 = __shfl_xor(xn0, 8), p1 = __shfl_xor(xn1, 8);
    float y0 = xn0, y1 = xn1;
    if (lane < 16) {
      float c0 = cosb[bs * ROT_ + d0], c1 = cosb[bs * ROT_ + d0 + 1];
      float s0 = sinb[bs * ROT_ + d0], s1 = sinb[bs * ROT_ + d0 + 1];
      float sgn = (lane < 8) ? -1.0f : 1.0f;
      y0 = xn0 * c0 + sgn * p0 * s0;
      y1 = xn1 * c1 + sgn * p1 * s1;
    }
    float g = ge[s];
    unsigned int pack = (unsigned int)f2b(y0 * g) | ((unsigned int)f2b(y1 * g) << 16);
    size_t off = (size_t)(b * KV_ + kvb) * 262144
               + (size_t)((s >> 4) * 4 + (d0 >> 5)) * 512
               + (size_t)(((s & 15) + (((d0 >> 3) & 3)) * 16)) * 8 + (d0 & 7);
    *(unsigned int*)(kF + off) = pack;
  } else {
    int bx  = bxx - 2048;
    int scn = bx & 7, d = (bx >> 3) & 127, kvb = (bx >> 10) & 1, b = bx >> 11;
    int s = scn * 256 + threadIdx.x;
    float v = b2f(qgkv[((long)(b * S_ + s)) * QGS + 4352 + kvb * 128 + d]);
    v *= ge[s];
    size_t off = (size_t)(b * KV_ + kvb) * 262144
               + (size_t)((s >> 6) * 16 + (d >> 4) * 2 + ((s >> 5) & 1)) * 512
               + (size_t)((d & 15) + ((s >> 3) & 3) * 16) * 8 + (s & 7);
    vF[off] = f2b(v);
  }
}

// ---------------- flash attention: 256-thr block = 4 waves = 4 strips of ONE head ----------------
__global__ __launch_bounds__(256) void k_attn(const unsigned short* __restrict__ qgkv,
                                              const unsigned short* __restrict__ kF,
                                              const unsigned short* __restrict__ vF,
                                              const float* __restrict__ kbias,
                                              const float* __restrict__ cosb,
                                              const float* __restrict__ sinb,
                                              const float* __restrict__ qnw,
                                              unsigned short* __restrict__ ag) {
  __shared__ __align__(16) unsigned short KL[2][8192];   // 2 x 16 KB K tile
  __shared__ __align__(16) unsigned short Ps[4][16 * 88];
  const int t = threadIdx.x;
  const int lane = t & 63, wv = t >> 6;
  const int r15 = lane & 15, g4 = lane >> 4;
  const int p = blockIdx.x;
  const int xcd = p & 7;
  const int grp = xcd >> 1;
  const int mem = ((p >> 3) << 1) | (xcd & 1);
  const int head = mem & 7;
  const int quad = 31 - (mem >> 3);
  const int b = grp >> 1, kvh = grp & 1;
  const int hh = kvh * 8 + head;
  const int strip = quad * 4 + wv;
  const int q0s = strip * 16;
  const int ntiles = quad + 1;

  const unsigned short* kFg = kF + (size_t)(b * KV_ + kvh) * 262144;
  const unsigned short* vFg = vF + (size_t)(b * KV_ + kvh) * 262144;

  // ---- load q row (q0s + r15) and apply RMS norm + RoPE in-register ----
  short8 qf[4];
  {
    const int q = q0s + r15;
    const unsigned short* qp = qgkv + ((size_t)(b * S_) + q) * QGS + hh * 256 + g4 * 8;
    float xn[4][8];
    float ssq = 0.f;
#pragma unroll
    for (int kb = 0; kb < 4; kb++) {
      short8 qr = *(const short8*)(qp + kb * 32);
#pragma unroll
      for (int e = 0; e < 8; e++) {
        float x = b2f((unsigned short)qr[e]);
        xn[kb][e] = x;
        ssq += x * x;
      }
    }
    ssq += __shfl_xor(ssq, 16);
    ssq += __shfl_xor(ssq, 32);
    float rstd = rsqrtf(ssq * (1.0f / 128.0f) + 1e-6f);
#pragma unroll
    for (int kb = 0; kb < 4; kb++) {
      float4 w0 = *(const float4*)(&qnw[kb * 32 + g4 * 8]);
      float4 w1 = *(const float4*)(&qnw[kb * 32 + g4 * 8 + 4]);
      xn[kb][0] *= rstd * w0.x; xn[kb][1] *= rstd * w0.y;
      xn[kb][2] *= rstd * w0.z; xn[kb][3] *= rstd * w0.w;
      xn[kb][4] *= rstd * w1.x; xn[kb][5] *= rstd * w1.y;
      xn[kb][6] *= rstd * w1.z; xn[kb][7] *= rstd * w1.w;
    }
    {
      const float* cbp = cosb + ((size_t)(b * S_) + q) * ROT_ + g4 * 8;
      const float* sbp = sinb + ((size_t)(b * S_) + q) * ROT_ + g4 * 8;
      float4 c0 = *(const float4*)(cbp), c1 = *(const float4*)(cbp + 4);
      float4 s0 = *(const float4*)(sbp), s1 = *(const float4*)(sbp + 4);
      float cv[8] = {c0.x, c0.y, c0.z, c0.w, c1.x, c1.y, c1.z, c1.w};
      float sv[8] = {s0.x, s0.y, s0.z, s0.w, s1.x, s1.y, s1.z, s1.w};
      float sgn = (g4 < 2) ? -1.0f : 1.0f;
#pragma unroll
      for (int e = 0; e < 8; e++) {
        float part = __shfl_xor(xn[0][e], 32);
        xn[0][e] = xn[0][e] * cv[e] + sgn * part * sv[e];
      }
    }
#pragma unroll
    for (int kb = 0; kb < 4; kb++)
#pragma unroll
      for (int e = 0; e < 8; e++) qf[kb][e] = (short)f2b(xn[kb][e]);
  }

  floatx4 oacc[8];
#pragma unroll
  for (int nd = 0; nd < 8; nd++) oacc[nd] = (floatx4){0.f, 0.f, 0.f, 0.f};
  float mrow = -1e30f, lrw = 0.f;

#pragma unroll
  for (int i = 0; i < 4; i++)
    gload_lds16(kFg + (size_t)wv * 2048 + i * 512 + lane * 8, &KL[0][wv * 2048 + i * 512]);
  __syncthreads();

  int cur = 0;
  for (int tile = 0; tile < ntiles; tile++) {
    if (tile + 1 < ntiles) {
      const size_t src = (size_t)(tile + 1) * 8192 + wv * 2048 + lane * 8;
#pragma unroll
      for (int i = 0; i < 4; i++)
        gload_lds16(kFg + src + i * 512, &KL[cur ^ 1][wv * 2048 + i * 512]);
    }

    floatx4 sacc[4];
#pragma unroll
    for (int n = 0; n < 4; n++) sacc[n] = (floatx4){0.f, 0.f, 0.f, 0.f};
    __builtin_amdgcn_s_setprio(1);
#pragma unroll
    for (int n = 0; n < 4; n++) {
      const unsigned short* kl = &KL[cur][n * 2048 + lane * 8];
      short8 a0 = *(const short8*)(kl);
      short8 a1 = *(const short8*)(kl + 512);
      short8 a2 = *(const short8*)(kl + 1024);
      short8 a3 = *(const short8*)(kl + 1536);
      sacc[n] = __builtin_amdgcn_mfma_f32_16x16x32_bf16(a0, qf[0], sacc[n], 0, 0, 0);
      sacc[n] = __builtin_amdgcn_mfma_f32_16x16x32_bf16(a1, qf[1], sacc[n], 0, 0, 0);
      sacc[n] = __builtin_amdgcn_mfma_f32_16x16x32_bf16(a2, qf[2], sacc[n], 0, 0, 0);
      sacc[n] = __builtin_amdgcn_mfma_f32_16x16x32_bf16(a3, qf[3], sacc[n], 0, 0, 0);
    }
    __builtin_amdgcn_s_setprio(0);

    const unsigned short* vt = vFg + (size_t)tile * 8192 + lane * 8;
    short8 vfA[8];
#pragma unroll
    for (int nd = 0; nd < 8; nd++) vfA[nd] = *(const short8*)(vt + (nd * 2) * 512);

    const bool last = (tile == ntiles - 1);
    float scf[4][4];
#pragma unroll
    for (int n = 0; n < 4; n++) {
      const int j0 = tile * 64;
      float4 kb4 = *(const float4*)(&kbias[j0 + n * 16 + g4 * 4]);
#pragma unroll
      for (int i = 0; i < 4; i++) {
        float kbv = (i == 0) ? kb4.x : (i == 1) ? kb4.y : (i == 2) ? kb4.z : kb4.w;
        float v = sacc[n][i] * SCALE_ + kbv;
        if (last) {
          int jg = j0 + n * 16 + g4 * 4 + i;
          if (jg > q0s + r15) v = -1e30f;
        }
        scf[n][i] = v;
      }
    }
    float pmax = scf[0][0];
#pragma unroll
    for (int n = 0; n < 4; n++)
#pragma unroll
      for (int i = 0; i < 4; i++) pmax = fmaxf(pmax, scf[n][i]);
    pmax = fmaxf(pmax, __shfl_xor(pmax, 16));
    pmax = fmaxf(pmax, __shfl_xor(pmax, 32));
    if (__any(pmax > mrow + 8.0f)) {
      float mn = fmaxf(mrow, pmax);
      float aq = __expf(mrow - mn);
      mrow = mn;
      lrw *= aq;
      float ai[4];
#pragma unroll
      for (int i = 0; i < 4; i++) ai[i] = __shfl(aq, g4 * 4 + i);
#pragma unroll
      for (int nd = 0; nd < 8; nd++)
#pragma unroll
        for (int i = 0; i < 4; i++) oacc[nd][i] *= ai[i];
    }
    float rsum = 0.f;
#pragma unroll
    for (int n = 0; n < 4; n++)
#pragma unroll
      for (int i = 0; i < 4; i++) {
        float pv = __expf(scf[n][i] - mrow);
        scf[n][i] = pv;
        rsum += pv;
      }
    rsum += __shfl_xor(rsum, 16);
    rsum += __shfl_xor(rsum, 32);
    lrw += rsum;

#pragma unroll
    for (int n = 0; n < 4; n++) {
      unsigned int lo = (unsigned int)f2b(scf[n][0]) | ((unsigned int)f2b(scf[n][1]) << 16);
      unsigned int hi = (unsigned int)f2b(scf[n][2]) | ((unsigned int)f2b(scf[n][3]) << 16);
      uint2 w; w.x = lo; w.y = hi;
      *(uint2*)(&Ps[wv][r15 * 88 + n * 16 + g4 * 4]) = w;
    }

    short8 vfB[8];
#pragma unroll
    for (int nd = 0; nd < 8; nd++) vfB[nd] = *(const short8*)(vt + (nd * 2 + 1) * 512);

    {
      __builtin_amdgcn_s_setprio(1);
      short8 pa0 = *(const short8*)(&Ps[wv][r15 * 88 + g4 * 8]);
#pragma unroll
      for (int nd = 0; nd < 8; nd++)
        oacc[nd] = __builtin_amdgcn_mfma_f32_16x16x32_bf16(pa0, vfA[nd], oacc[nd], 0, 0, 0);
      short8 pa1 = *(const short8*)(&Ps[wv][r15 * 88 + 32 + g4 * 8]);
#pragma unroll
      for (int nd = 0; nd < 8; nd++)
        oacc[nd] = __builtin_amdgcn_mfma_f32_16x16x32_bf16(pa1, vfB[nd], oacc[nd], 0, 0, 0);
      __builtin_amdgcn_s_setprio(0);
    }
    __syncthreads();
    cur ^= 1;
  }

  float il[4];
#pragma unroll
  for (int i = 0; i < 4; i++) il[i] = __shfl(lrw, g4 * 4 + i);
#pragma unroll
  for (int i = 0; i < 4; i++) {
    int q = q0s + g4 * 4 + i;
    float inv = 1.0f / il[i];
    const unsigned short* gptr = qgkv + ((size_t)(b * S_ + q)) * QGS + hh * 256 + 128;
    unsigned short* aptr = ag + ((size_t)(b * S_ + q)) * (H_ * D_) + hh * D_;
#pragma unroll
    for (int nd = 0; nd < 8; nd++) {
      int d = nd * 16 + r15;
      float gt = b2f(gptr[d]);
      float sg = 1.0f / (1.0f + __expf(-gt));
      aptr[d] = f2b(oacc[nd][i] * inv * sg);
    }
  }
}

extern "C" void kernel_launch(void* const* d_in, const int* in_sizes, int n_in,
                              void* d_out, int out_size, void* d_ws, size_t ws_size,
                              hipStream_t stream) {
  const float* h_f   = (const float*)d_in[0];
  const float* cosb  = (const float*)d_in[1];
  const float* sinb  = (const float*)d_in[2];
  const float* prior = (const float*)d_in[4];
  const float* Wq    = (const float*)d_in[5];
  const float* Wk    = (const float*)d_in[6];
  const float* Wv    = (const float*)d_in[7];
  const float* Wo    = (const float*)d_in[8];
  const float* qnw   = (const float*)d_in[9];
  const float* knw   = (const float*)d_in[10];

  char* ws = (char*)d_ws;
  size_t off = 0;
  auto alloc = [&](size_t bytes) { char* p = ws + off; off += (bytes + 255) & ~(size_t)255; return p; };
  unsigned short* hb    = (unsigned short*)alloc((size_t)4096 * 2048 * 2);
  unsigned short* WqkvT = (unsigned short*)alloc((size_t)4608 * 2048 * 2);  // Wq|Wk|Wv transposed
  unsigned short* WoT   = (unsigned short*)alloc((size_t)2048 * 2048 * 2);
  unsigned short* qgkv  = (unsigned short*)alloc((size_t)4096 * QGS * 2);   // combined qg|k|v
  unsigned short* kF    = (unsigned short*)alloc((size_t)B_ * KV_ * S_ * D_ * 2);
  unsigned short* vF    = (unsigned short*)alloc((size_t)B_ * KV_ * S_ * D_ * 2);
  float* ge    = (float*)alloc((size_t)S_ * 4);
  float* kbias = (float*)alloc((size_t)S_ * 4);
  // Aliasing (sequential stream order): ag reuses hb (dead after the projection GEMM).
  unsigned short* ag = hb;

  dim3 blk(256);
  k_preproc<<<dim3(7432), blk, 0, stream>>>(h_f, prior, Wq, Wk, Wv, Wo,
                                            hb, WqkvT, WoT, ge, kbias);
  k_gemm_bt<0><<<dim3(36, 32), blk, 0, stream>>>(hb, WqkvT, qgkv, 4096, QGS, 2048);
  k_qkvpost<<<dim3(6144), blk, 0, stream>>>(qgkv, cosb, sinb, ge, knw, kF, vF);
  k_attn<<<dim3(1024), blk, 0, stream>>>(qgkv, kF, vF, kbias, cosb, sinb, qnw, ag);
  k_gemm_bt<1><<<dim3(16, 32), blk, 0, stream>>>(ag, WoT, d_out, 4096, 2048, 2048);
}